// Round 20
// baseline (937.009 us; speedup 1.0000x reference)
//
#include <hip/hip_runtime.h>
#include <math.h>

#define NN 4096
#define FF 128
#define CD 100
#define OT_ITERS 20
#define RVAL (1.0f/4096.0f)
#define EK 8192
#define KS 32
#define CHUNK 32
#define NCH 128

typedef unsigned int uint;
typedef unsigned short ushort;
typedef unsigned long long ull;
typedef __attribute__((ext_vector_type(8))) short bf16x8;
typedef __attribute__((ext_vector_type(4))) float f32x4;

// ---------- bf16 helpers ----------
__device__ __forceinline__ float bflo(uint u){ return __uint_as_float(u << 16); }
__device__ __forceinline__ float bfhi(uint u){ return __uint_as_float(u & 0xFFFF0000u); }
__device__ __forceinline__ float bf2f(ushort s){ return __uint_as_float((uint)s << 16); }
__device__ __forceinline__ ushort f2bf(float x){
  uint u = __float_as_uint(x);
  u += 0x7FFFu + ((u >> 16) & 1u);
  return (ushort)(u >> 16);
}
__device__ __forceinline__ void unpack8(uint4 kk, float* e){
  e[0]=bflo(kk.x); e[1]=bfhi(kk.x); e[2]=bflo(kk.y); e[3]=bfhi(kk.y);
  e[4]=bflo(kk.z); e[5]=bfhi(kk.z); e[6]=bflo(kk.w); e[7]=bfhi(kk.w);
}
__device__ __forceinline__ uint4 pack8(const float* e){
  union { ushort us[8]; uint4 u4; } pk;
#pragma unroll
  for (int k=0;k<8;++k) pk.us[k]=f2bf(e[k]);
  return pk.u4;
}

// ---------- 4-bit linear codec: K in [e^-1, 1]; K = A4 + B4*n ----------
#define A4 0.36787944f
#define B4 0.042141372f
#define INVB4 23.729603f
__device__ __forceinline__ uint e4(float f){
  float q = (f - A4) * INVB4;
  int n = (int)(q + 0.5f);
  n = n < 0 ? 0 : (n > 15 ? 15 : n);
  return (uint)n;
}
__device__ __forceinline__ void d4x8(uint w, float* e){
#pragma unroll
  for (int k=0;k<8;++k)
    e[k] = A4 + B4 * (float)((w >> (4*k)) & 15u);
}

// ---------- wave/block reduce helpers (wave = 64) ----------
__device__ __forceinline__ float waveSum(float v){
#pragma unroll
  for (int o=32;o>0;o>>=1) v += __shfl_down(v,o);
  return v;
}
__device__ __forceinline__ float waveMax(float v){
#pragma unroll
  for (int o=32;o>0;o>>=1) v = fmaxf(v,__shfl_down(v,o));
  return v;
}
__device__ __forceinline__ float waveMin(float v){
#pragma unroll
  for (int o=32;o>0;o>>=1) v = fminf(v,__shfl_down(v,o));
  return v;
}
__device__ __forceinline__ float blkSum(float v, float* red){
  v = waveSum(v);
  if ((threadIdx.x&63)==0) red[threadIdx.x>>6] = v;
  __syncthreads();
  float r = red[0]+red[1]+red[2]+red[3];
  __syncthreads();
  return r;
}

// ---------- W transpose+convert (both weights): Wt[z][n][k] bf16 ----------
__global__ __launch_bounds__(256) void transposeW2(const float* __restrict__ W0,
                                                   const float* __restrict__ W1,
                                                   ushort* __restrict__ Wtb)
{
  __shared__ ushort T[128][72];
  const int z = blockIdx.y;
  const float* W = z ? W1 : W0;
  ushort* Wt = Wtb + (size_t)z*FF*EK;
  const int k0 = blockIdx.x*64, tid = threadIdx.x;
#pragma unroll
  for (int it=0; it<8; ++it){
    int f = tid + it*256;
    int r = f >> 5, c4 = f & 31;
    float4 v = *(const float4*)&W[(size_t)(k0+r)*FF + c4*4];
    T[c4*4+0][r]=f2bf(v.x); T[c4*4+1][r]=f2bf(v.y);
    T[c4*4+2][r]=f2bf(v.z); T[c4*4+3][r]=f2bf(v.w);
  }
  __syncthreads();
#pragma unroll
  for (int it=0; it<4; ++it){
    int f = tid + it*256;
    int n = f >> 3, c8 = f & 7;
    *(uint4*)&Wt[(size_t)n*EK + k0 + c8*8] = *(uint4*)&T[n][c8*8];
  }
}

// ---------- MFMA embed GEMM, both matrices, split-K=32, NT, bf16 partials ----------
__global__ __launch_bounds__(256) void embed_mfma2(const float* __restrict__ A0,
                                                   const float* __restrict__ A1,
                                                   const ushort* __restrict__ Wtb,
                                                   ushort* __restrict__ partb)
{
  __shared__ char smem[64*72*2 + 128*72*2];
  ushort (*Al)[72] = (ushort(*)[72])smem;
  ushort (*Wl)[72] = (ushort(*)[72])(smem + 64*72*2);
  float  (*Cst)[130] = (float(*)[130])smem;

  const int tid = threadIdx.x;
  const int z = blockIdx.z;
  const float* A = z ? A1 : A0;
  const ushort* Wt = Wtb + (size_t)z*FF*EK;
  ushort* part = partb + (size_t)z*KS*NN*FF;
  const int m0 = blockIdx.x * 64;
  const int kc = blockIdx.y * (EK/KS);
  const int w = tid >> 6, l = tid & 63;
  const int wr = w >> 1, wc = w & 1;
  const int lrow = l & 15, lk = (l >> 4) * 8;
  f32x4 acc[2][4];
#pragma unroll
  for (int mi=0;mi<2;++mi)
#pragma unroll
    for (int ni=0;ni<4;++ni) acc[mi][ni] = (f32x4){0.f,0.f,0.f,0.f};

  f32x4 aReg[4];
  uint4  wReg[4];
  auto gload = [&](int k0){
#pragma unroll
    for (int it=0;it<4;++it){
      int f = tid + it*256;
      int r = f >> 4, c4 = f & 15;
      aReg[it] = __builtin_nontemporal_load((const f32x4*)&A[(size_t)(m0+r)*EK + k0 + c4*4]);
    }
#pragma unroll
    for (int it=0;it<4;++it){
      int f = tid + it*256;
      int r = f >> 3, c8 = f & 7;
      wReg[it] = *(const uint4*)&Wt[(size_t)r*EK + k0 + c8*8];
    }
  };

  const int NSTEP = (EK/KS)/64;
  gload(kc);
  for (int step=0; step<NSTEP; ++step){
    __syncthreads();
#pragma unroll
    for (int it=0;it<4;++it){
      int f = tid + it*256;
      int r = f >> 4, c4 = f & 15;
      f32x4 a4 = aReg[it];
      union { ushort us[4]; uint2 u2; } pk;
      pk.us[0]=f2bf(a4[0]); pk.us[1]=f2bf(a4[1]); pk.us[2]=f2bf(a4[2]); pk.us[3]=f2bf(a4[3]);
      *(uint2*)&Al[r][c4*4] = pk.u2;
    }
#pragma unroll
    for (int it=0;it<4;++it){
      int f = tid + it*256;
      int r = f >> 3, c8 = f & 7;
      *(uint4*)&Wl[r][c8*8] = wReg[it];
    }
    __syncthreads();
    if (step+1 < NSTEP) gload(kc + (step+1)*64);
#pragma unroll
    for (int ksub = 0; ksub < 2; ++ksub) {
      bf16x8 af[2], bfr[4];
#pragma unroll
      for (int mi=0;mi<2;++mi) af[mi] = *(bf16x8*)&Al[wr*32+mi*16+lrow][ksub*32+lk];
#pragma unroll
      for (int ni=0;ni<4;++ni) bfr[ni] = *(bf16x8*)&Wl[wc*64+ni*16+lrow][ksub*32+lk];
#pragma unroll
      for (int mi=0;mi<2;++mi)
#pragma unroll
        for (int ni=0;ni<4;++ni)
          acc[mi][ni] = __builtin_amdgcn_mfma_f32_16x16x32_bf16(af[mi], bfr[ni], acc[mi][ni], 0,0,0);
    }
  }
  // ---- coalesced epilogue: stage fp32 in LDS, store bf16 NT (ull) ----
#pragma unroll
  for (int half=0; half<2; ++half){
    __syncthreads();
    if (wr == half){
#pragma unroll
      for (int mi=0;mi<2;++mi)
#pragma unroll
        for (int ni=0;ni<4;++ni)
#pragma unroll
          for (int r=0;r<4;++r){
            int rr = mi*16 + (l>>4)*4 + r;
            int col = wc*64 + ni*16 + lrow;
            Cst[rr][col] = acc[mi][ni][r];
          }
    }
    __syncthreads();
#pragma unroll
    for (int it=0;it<4;++it){
      int f = tid + it*256;
      int rr = f >> 5, g = f & 31;
      float4 o = *(float4*)&Cst[rr][g*4];
      union { ushort us[4]; ull u8; } pk;
      pk.us[0]=f2bf(o.x); pk.us[1]=f2bf(o.y); pk.us[2]=f2bf(o.z); pk.us[3]=f2bf(o.w);
      __builtin_nontemporal_store(pk.u8,
        (ull*)&part[((size_t)blockIdx.y*NN + m0 + half*32 + rr)*FF + g*4]);
    }
  }
}

// ---------- reduce bf16 split-K partials + bias + l2norm, both matrices ----------
__global__ __launch_bounds__(128) void reduce_l2_2(const ushort* __restrict__ partb,
                                                   const float* __restrict__ b0,
                                                   const float* __restrict__ b1,
                                                   float* __restrict__ o0,
                                                   float* __restrict__ o1,
                                                   ushort* __restrict__ ob0,
                                                   ushort* __restrict__ ob1)
{
  __shared__ float red[2];
  const int z = blockIdx.y;
  const ushort* part = partb + (size_t)z*KS*NN*FF;
  const float* bias = z ? b1 : b0;
  float* out = z ? o1 : o0;
  ushort* outb = z ? ob1 : ob0;
  int i = blockIdx.x, t = threadIdx.x;
  float s = bias[t];
#pragma unroll
  for (int ks=0; ks<KS; ++ks) s += bf2f(part[((size_t)ks*NN + i)*FF + t]);
  float q = waveSum(s*s);
  if ((t&63)==0) red[t>>6]=q;
  __syncthreads();
  float val = s / sqrtf(red[0]+red[1]);
  out[(size_t)i*FF+t] = val;
  outb[(size_t)i*FF+t] = f2bf(val);
}

// ---------- softmax rows (both): Sb bf16 [4096][128] padded, w = ||S_row|| ----------
__global__ __launch_bounds__(128) void softmax_rows2(const float* __restrict__ l0,
                                                     const float* __restrict__ l1,
                                                     ushort* __restrict__ Sb0,
                                                     ushort* __restrict__ Sb1,
                                                     float* __restrict__ w0,
                                                     float* __restrict__ w1)
{
  __shared__ float sm[2], ss[2], sq[2];
  const int z = blockIdx.y;
  const float* l = z ? l1 : l0;
  ushort* Sb = z ? Sb1 : Sb0;
  float* w = z ? w1 : w0;
  int i = blockIdx.x, t = threadIdx.x;
  int lane = t & 63, wid = t >> 6;
  float x = (t < CD) ? l[(size_t)i*CD + t] : -3.4e38f;
  float m = waveMax(x);
  if (lane==0) sm[wid]=m;
  __syncthreads();
  m = fmaxf(sm[0], sm[1]);
  float e = (t < CD) ? __expf(x - m) : 0.f;
  float s = waveSum(e);
  if (lane==0) ss[wid]=s;
  __syncthreads();
  float tot = ss[0]+ss[1];
  float sv = e / tot;
  Sb[(size_t)i*FF + t] = (t < CD) ? f2bf(sv) : (ushort)0;
  float q = waveSum(sv*sv);
  if (lane==0) sq[wid]=q;
  __syncthreads();
  if (t==0) w[i] = sqrtf(sq[0]+sq[1]);
}

// ---------- top-7 select from raw bf16 dot matrix, both matrices ----------
__global__ __launch_bounds__(256) void knn_select2(const ushort* __restrict__ Ds,
                                                   const ushort* __restrict__ Dt,
                                                   const float* __restrict__ w_s,
                                                   const float* __restrict__ w_t,
                                                   int* __restrict__ idx_s,
                                                   int* __restrict__ idx_t)
{
  __shared__ float redv[256];
  __shared__ int   redi[256];
  const int z = blockIdx.y;
  const ushort* D = z ? Dt : Ds;
  const float* w = z ? w_t : w_s;
  int* idx = z ? idx_t : idx_s;
  int i = blockIdx.x, tid = threadIdx.x;
  float wi = w[i];
  float bv[7]; int bi[7];
#pragma unroll
  for (int m=0;m<7;++m){ bv[m]=-3.4e38f; bi[m]=-1; }
  const uint4* row4 = (const uint4*)&D[(size_t)i*NN];
#pragma unroll
  for (int ss=0;ss<2;++ss){
    int j8 = tid + ss*256;
    float e[8]; unpack8(row4[j8], e);
#pragma unroll
    for (int q=0;q<8;++q){
      int j = j8*8 + q;
      float cv = e[q] / fmaxf(wi * w[j], 1e-7f);
      cv = (j==i) ? -3.4e38f : cv;
      if (cv > bv[6]) {
        int m = 6;
        while (m > 0 && cv > bv[m-1]) { bv[m]=bv[m-1]; bi[m]=bi[m-1]; --m; }
        bv[m]=cv; bi[m]=j;
      }
    }
  }
  if (tid==0) idx[(size_t)i*8] = i;
  for (int m=0;m<7;++m) {
    redv[tid]=bv[0]; redi[tid]=tid;
    __syncthreads();
    for (int s=128;s>=1;s>>=1) {
      if (tid < s) {
        if (redv[tid+s] > redv[tid]) { redv[tid]=redv[tid+s]; redi[tid]=redi[tid+s]; }
      }
      __syncthreads();
    }
    int wt = redi[0];
    if (tid == wt) {
      idx[(size_t)i*8 + 1 + m] = bi[0];
#pragma unroll
      for (int q=0;q<6;++q){ bv[q]=bv[q+1]; bi[q]=bi[q+1]; }
      bv[6]=-3.4e38f; bi[6]=-1;
    }
    __syncthreads();
  }
}

// ---------- encoder (both): outb = bf16(l2norm(concat(h, mean(h[idx])) @ W + b)) ----------
__global__ __launch_bounds__(128) void encoder_kernel2(const float* __restrict__ h0,
                                                       const float* __restrict__ h1,
                                                       const int* __restrict__ idx0,
                                                       const int* __restrict__ idx1,
                                                       const float* __restrict__ W0,
                                                       const float* __restrict__ W1,
                                                       const float* __restrict__ bb0,
                                                       const float* __restrict__ bb1,
                                                       ushort* __restrict__ o0,
                                                       ushort* __restrict__ o1)
{
  __shared__ float hin[256];
  __shared__ float sred[2];
  const int z = blockIdx.y;
  const float* h = z ? h1 : h0;
  const int* idx = z ? idx1 : idx0;
  const float* W = z ? W1 : W0;
  const float* bias = z ? bb1 : bb0;
  ushort* outb = z ? o1 : o0;
  int i = blockIdx.x, t = threadIdx.x;
  float hv = h[(size_t)i*FF + t];
  float agg = 0.f;
#pragma unroll
  for (int m=0;m<8;++m) agg += h[(size_t)idx[i*8+m]*FF + t];
  agg *= 0.125f;
  hin[t] = hv; hin[FF + t] = agg;
  __syncthreads();
  float acc = bias[t];
  for (int k=0;k<256;++k) acc += hin[k] * W[(size_t)k*FF + t];
  float s = waveSum(acc*acc);
  int lane = t & 63, wid = t >> 6;
  if (lane==0) sred[wid]=s;
  __syncthreads();
  float tot = sred[0]+sred[1];
  outb[(size_t)i*FF + t] = f2bf(acc / sqrtf(tot));
}

// ---------- MFMA: C bf16 = A bf16 @ B^T, z-select inputs, optional stats ----------
__global__ __launch_bounds__(256) void gemm_btb_mfma(const ushort* __restrict__ A0,
                                                     const ushort* __restrict__ B0,
                                                     ushort* __restrict__ C0,
                                                     const ushort* __restrict__ A1,
                                                     const ushort* __restrict__ B1,
                                                     ushort* __restrict__ C1,
                                                     float* __restrict__ rmaxp,
                                                     float* __restrict__ gminp)
{
  __shared__ ushort Al[64][136];
  __shared__ ushort Bl[64][136];
  __shared__ float rmx2[64][2];
  __shared__ float gmnw[4];
  const int z = blockIdx.z;
  const ushort* A = z ? A1 : A0;
  const ushort* B = z ? B1 : B0;
  ushort* C = z ? C1 : C0;
  const int tid = threadIdx.x;
  const int i0 = blockIdx.y*64, j0 = blockIdx.x*64;
#pragma unroll
  for (int it=0; it<4; ++it){
    int f = tid + it*256;
    int r = f >> 4, c8 = f & 15;
    *(uint4*)&Al[r][c8*8] = *(const uint4*)&A[(size_t)(i0+r)*FF + c8*8];
    *(uint4*)&Bl[r][c8*8] = *(const uint4*)&B[(size_t)(j0+r)*FF + c8*8];
  }
  __syncthreads();
  const int w = tid>>6, l = tid&63;
  const int wr = w>>1, wc = w&1;
  const int lrow = l&15, lk = (l>>4)*8;
  f32x4 acc[2][2];
#pragma unroll
  for (int mi=0;mi<2;++mi)
#pragma unroll
    for (int ni=0;ni<2;++ni) acc[mi][ni] = (f32x4){0.f,0.f,0.f,0.f};
#pragma unroll
  for (int ks=0; ks<4; ++ks){
    bf16x8 af[2], bfm[2];
#pragma unroll
    for (int mi=0;mi<2;++mi) af[mi] = *(bf16x8*)&Al[wr*32+mi*16+lrow][ks*32+lk];
#pragma unroll
    for (int ni=0;ni<2;++ni) bfm[ni] = *(bf16x8*)&Bl[wc*32+ni*16+lrow][ks*32+lk];
#pragma unroll
    for (int mi=0;mi<2;++mi)
#pragma unroll
      for (int ni=0;ni<2;++ni)
        acc[mi][ni] = __builtin_amdgcn_mfma_f32_16x16x32_bf16(af[mi], bfm[ni], acc[mi][ni], 0,0,0);
  }
  if (rmaxp){
    float rowm[8]; float gmn = 3.4e38f;
#pragma unroll
    for (int mi=0;mi<2;++mi)
#pragma unroll
      for (int r=0;r<4;++r){
        float a = fmaxf(acc[mi][0][r], acc[mi][1][r]);
        float c = fminf(acc[mi][0][r], acc[mi][1][r]);
        rowm[mi*4+r] = a;
        gmn = fminf(gmn, c);
      }
#pragma unroll
    for (int mo=1; mo<16; mo<<=1){
#pragma unroll
      for (int q=0;q<8;++q) rowm[q] = fmaxf(rowm[q], __shfl_xor(rowm[q], mo));
      gmn = fminf(gmn, __shfl_xor(gmn, mo));
    }
    if (lrow == 0){
#pragma unroll
      for (int mi=0;mi<2;++mi)
#pragma unroll
        for (int r=0;r<4;++r)
          rmx2[wr*32 + mi*16 + (l>>4)*4 + r][wc] = rowm[mi*4+r];
    }
    gmn = fminf(gmn, __shfl_xor(gmn, 16));
    gmn = fminf(gmn, __shfl_xor(gmn, 32));
    if (l==0) gmnw[w] = gmn;
    __syncthreads();
    if (tid < 64)
      rmaxp[(size_t)blockIdx.x*NN + i0 + tid] = fmaxf(rmx2[tid][0], rmx2[tid][1]);
    if (tid == 0)
      gminp[blockIdx.y*64 + blockIdx.x] = fminf(fminf(gmnw[0],gmnw[1]),fminf(gmnw[2],gmnw[3]));
  }
  __syncthreads();
  ushort (*Cl)[72] = (ushort(*)[72])&Al[0][0];
#pragma unroll
  for (int mi=0;mi<2;++mi)
#pragma unroll
    for (int ni=0;ni<2;++ni)
#pragma unroll
      for (int r=0;r<4;++r){
        int row = wr*32 + mi*16 + (l>>4)*4 + r;
        int col = wc*32 + ni*16 + lrow;
        Cl[row][col] = f2bf(acc[mi][ni][r]);
      }
  __syncthreads();
#pragma unroll
  for (int it=0; it<2; ++it){
    int f = tid + it*256;
    int r = f >> 3, c8 = f & 7;
    *(uint4*)&C[(size_t)(i0+r)*NN + j0 + c8*8] = *(uint4*)&Cl[r][c8*8];
  }
}

// ---------- rowmax finalize: 4 threads per row (64 blocks) ----------
__global__ __launch_bounds__(256) void rowstat2(const float* __restrict__ rmaxp,
                                                float* __restrict__ rmax)
{
  int t = threadIdx.x;
  int row = blockIdx.x*64 + (t >> 2);
  int q = t & 3;
  float m = -3.4e38f;
#pragma unroll
  for (int b=0;b<16;++b) m = fmaxf(m, rmaxp[(size_t)(q*16+b)*NN + row]);
  m = fmaxf(m, __shfl_xor(m, 1));
  m = fmaxf(m, __shfl_xor(m, 2));
  if (q==0) rmax[row] = m;
}

// ---------- stat finalize: stat = {gmin, 1/(gmax-gmin)} ----------
__global__ __launch_bounds__(256) void greduce_s(const float* __restrict__ rmax,
                                                 const float* __restrict__ gminp,
                                                 float* __restrict__ stat)
{
  __shared__ float r1[4], r2[4];
  int t = threadIdx.x;
  float mx=-3.4e38f, mn=3.4e38f;
  for (int i=t; i<NN; i+=256){
    mx = fmaxf(mx, rmax[i]);
    mn = fminf(mn, gminp[i]);
  }
  mx = waveMax(mx); mn = waveMin(mn);
  int lane = t & 63, wid = t >> 6;
  if (lane==0){ r1[wid]=mx; r2[wid]=mn; }
  __syncthreads();
  if (t==0){
    float gmx = fmaxf(fmaxf(r1[0],r1[1]),fmaxf(r1[2],r1[3]));
    float gmn = fminf(fminf(r2[0],r2[1]),fminf(r2[2],r2[3]));
    stat[0] = gmn;
    stat[1] = 1.f/(gmx-gmn);
  }
}

// ---------- single-matrix: K4 = 4bit(exp((M0 - rowmax)*scale)); optional M out ----------
__global__ __launch_bounds__(256) void transform_s(const ushort* __restrict__ stage,
                                                   uint* __restrict__ K4m,
                                                   const float* __restrict__ rmax,
                                                   const float* __restrict__ stat,
                                                   float* __restrict__ Mout)
{
  const float gmin = stat[0], scale = stat[1];
  const uint4* Km = (const uint4*)stage;
  const bool wM = (Mout != nullptr);
  const int total8 = (NN*NN)/8;
  for (int f = blockIdx.x*256 + threadIdx.x; f < total8; f += gridDim.x*256){
    int i = f >> 9;
    float rm = rmax[i];
    float e[8]; unpack8(Km[f], e);
    uint o = 0;
#pragma unroll
    for (int k=0;k<8;++k) o |= e4(__expf((e[k]-rm)*scale)) << (4*k);
    K4m[f] = o;
    if (wM){
      float4 o1, o2;
      o1.x=(e[0]-gmin)*scale; o1.y=(e[1]-gmin)*scale; o1.z=(e[2]-gmin)*scale; o1.w=(e[3]-gmin)*scale;
      o2.x=(e[4]-gmin)*scale; o2.y=(e[5]-gmin)*scale; o2.z=(e[6]-gmin)*scale; o2.w=(e[7]-gmin)*scale;
      float4* mp = (float4*)(Mout + (size_t)f*8);
      mp[0]=o1; mp[1]=o2;
    }
  }
}

// ---------- init: v=1 for all 4 matrices ----------
__global__ void vinit4(float* __restrict__ v)
{
  int g = blockIdx.x*256 + threadIdx.x;
  if (g < 4*NN) v[g] = 1.f;
}

// ---------- fused sinkhorn iteration over 4-bit K, paired-row barriers ----------
__global__ __launch_bounds__(256) void sink_fused(const uint* __restrict__ K4base,
                                                  const float* __restrict__ vv,
                                                  ushort* __restrict__ part)
{
  __shared__ float red2[2][4];
  const int m = blockIdx.y, b = blockIdx.x, t = threadIdx.x;
  const int i0 = b*CHUNK;
  const uint* K4 = K4base + (size_t)m*NN*(NN/8);
  const float4* v4 = (const float4*)(vv + (size_t)m*NN);
  const int lane = t & 63, wid = t >> 6;
  float vs[16];
  {
    float4 A=v4[t*4+0], B=v4[t*4+1], C=v4[t*4+2], D=v4[t*4+3];
    vs[0]=A.x; vs[1]=A.y; vs[2]=A.z; vs[3]=A.w;
    vs[4]=B.x; vs[5]=B.y; vs[6]=B.z; vs[7]=B.w;
    vs[8]=C.x; vs[9]=C.y; vs[10]=C.z; vs[11]=C.w;
    vs[12]=D.x; vs[13]=D.y; vs[14]=D.z; vs[15]=D.w;
  }
  float vsum = 0.f;
#pragma unroll
  for (int k=0;k<16;++k) vsum += vs[k];
  float colacc[16];
#pragma unroll
  for (int k=0;k<16;++k) colacc[k]=0.f;
  for (int r=0;r<CHUNK;r+=2){
    uint2 kw0 = ((const uint2*)(K4 + (size_t)(i0+r  )*(NN/8)))[t];
    uint2 kw1 = ((const uint2*)(K4 + (size_t)(i0+r+1)*(NN/8)))[t];
    float s0 = 0.f, s1 = 0.f;
#pragma unroll
    for (int k=0;k<8;++k){
      s0 += (float)((kw0.x >> (4*k)) & 15u) * vs[k];
      s0 += (float)((kw0.y >> (4*k)) & 15u) * vs[k+8];
      s1 += (float)((kw1.x >> (4*k)) & 15u) * vs[k];
      s1 += (float)((kw1.y >> (4*k)) & 15u) * vs[k+8];
    }
    float d0 = waveSum(A4*vsum + B4*s0);
    float d1 = waveSum(A4*vsum + B4*s1);
    if (lane==0){ red2[0][wid]=d0; red2[1][wid]=d1; }
    __syncthreads();
    float ur0 = RVAL / (red2[0][0]+red2[0][1]+red2[0][2]+red2[0][3]);
    float ur1 = RVAL / (red2[1][0]+red2[1][1]+red2[1][2]+red2[1][3]);
    __syncthreads();
    const float a0 = A4*ur0 + A4*ur1;
    const float b0 = B4*ur0, b1 = B4*ur1;
#pragma unroll
    for (int k=0;k<8;++k){
      colacc[k]   += a0 + b0*(float)((kw0.x >> (4*k)) & 15u) + b1*(float)((kw1.x >> (4*k)) & 15u);
      colacc[k+8] += a0 + b0*(float)((kw0.y >> (4*k)) & 15u) + b1*(float)((kw1.y >> (4*k)) & 15u);
    }
  }
  ushort* prow = part + ((size_t)m*NCH + b)*NN;
  ((uint4*)prow)[t*2]   = pack8(colacc);
  ((uint4*)prow)[t*2+1] = pack8(colacc+8);
}

// ---------- column finish: v[j] = R / sum_b part[m][b][j]; 64 cols/block ----------
__global__ __launch_bounds__(256) void colfin_b(const ushort* __restrict__ part,
                                                float* __restrict__ vv)
{
  __shared__ float lds[32][8][9];
  const int m = blockIdx.y, bx = blockIdx.x, t = threadIdx.x;
  const int g = t & 7;
  const int tq = t >> 3;
  const uint4* pb = (const uint4*)(part + (size_t)m*NCH*NN);
  float acc[8];
#pragma unroll
  for (int k=0;k<8;++k) acc[k]=0.f;
#pragma unroll
  for (int s=0;s<4;++s){
    int b = tq + s*32;
    float e[8]; unpack8(pb[(size_t)b*512 + bx*8 + g], e);
#pragma unroll
    for (int k=0;k<8;++k) acc[k] += e[k];
  }
#pragma unroll
  for (int k=0;k<8;++k) lds[tq][g][k] = acc[k];
  __syncthreads();
  if (t < 64){
    int gg = t >> 3, c = t & 7;
    float s = 0.f;
#pragma unroll
    for (int q=0;q<32;++q) s += lds[q][gg][c];
    vv[(size_t)m*NN + bx*64 + gg*8 + c] = RVAL / s;
  }
}

// ---------- final: y = Kv ; P = K v_j / y ; per-row loss partial ----------
__global__ __launch_bounds__(256) void loss2_b(const uint* __restrict__ K4base,
                                               const float* __restrict__ vv,
                                               float* __restrict__ accf,
                                               float* __restrict__ Pout, int finalm)
{
  __shared__ float red[4];
  int m = blockIdx.y, i = blockIdx.x, t = threadIdx.x;
  const uint2* row = (const uint2*)(K4base + ((size_t)m*NN + i)*(NN/8));
  const float4* v4 = (const float4*)(vv + (size_t)m*NN);
  uint2 kw = row[t];
  float e[16];
  d4x8(kw.x, e); d4x8(kw.y, e+8);
  float vr[16];
  {
    float4 A=v4[t*4+0], B=v4[t*4+1], C=v4[t*4+2], D=v4[t*4+3];
    vr[0]=A.x; vr[1]=A.y; vr[2]=A.z; vr[3]=A.w;
    vr[4]=B.x; vr[5]=B.y; vr[6]=B.z; vr[7]=B.w;
    vr[8]=C.x; vr[9]=C.y; vr[10]=C.z; vr[11]=C.w;
    vr[12]=D.x; vr[13]=D.y; vr[14]=D.z; vr[15]=D.w;
  }
  float s = 0.f;
#pragma unroll
  for (int k=0;k<16;++k) s += e[k]*vr[k];
  float y = blkSum(s, red);
  float invy = 1.f / y;
  const bool wp = (m==finalm) && (Pout != nullptr);
  const int j0 = t*16;
  float p[16];
#pragma unroll
  for (int k=0;k<16;++k) p[k] = e[k]*vr[k]*invy;
  if (wp){
    float4* pp = (float4*)(Pout + (size_t)i*NN + j0);
#pragma unroll
    for (int q=0;q<4;++q){
      float4 o; o.x=p[q*4]; o.y=p[q*4+1]; o.z=p[q*4+2]; o.w=p[q*4+3];
      pp[q]=o;
    }
  }
  float local = 0.f;
#pragma unroll
  for (int k=0;k<16;++k){
    float d = p[k] - ((j0+k)==i ? 1.f : 0.f);
    local += d*d;
  }
  float tot = blkSum(local, red);
  if (t==0) accf[(size_t)m*NN + i] = tot;
}

// ---------- all four losses + total in one kernel ----------
__global__ __launch_bounds__(256) void lossfin_all(const float* __restrict__ accf,
                                                   float* __restrict__ out)
{
  __shared__ float red[4];
  int t = threadIdx.x;
  float L[4];
#pragma unroll
  for (int m=0;m<4;++m){
    float s = 0.f;
#pragma unroll
    for (int q=0;q<16;++q) s += accf[(size_t)m*NN + t + q*256];
    float tot = blkSum(s, red);
    L[m] = sqrtf(tot);
  }
  if (t==0){
    out[1]=L[0]; out[3]=L[1]; out[4]=L[2]; out[2]=L[3];
    out[0]=L[0]+L[1]+L[2]+L[3];
  }
}

extern "C" void kernel_launch(void* const* d_in, const int* in_sizes, int n_in,
                              void* d_out, int out_size, void* d_ws, size_t ws_size,
                              hipStream_t stream)
{
  (void)in_sizes; (void)n_in; (void)out_size; (void)ws_size;
  const float* f_s  = (const float*)d_in[1];
  const float* l_s  = (const float*)d_in[2];
  const float* f_t  = (const float*)d_in[3];
  const float* l_t  = (const float*)d_in[4];
  const float* W_es = (const float*)d_in[5];
  const float* b_es = (const float*)d_in[6];
  const float* W_et = (const float*)d_in[7];
  const float* b_et = (const float*)d_in[8];
  const float* W_gs = (const float*)d_in[9];
  const float* b_gs = (const float*)d_in[10];
  const float* W_gt = (const float*)d_in[11];
  const float* b_gt = (const float*)d_in[12];
  float* out = (float*)d_out;

  char* ws = (char*)d_ws;
  size_t off = 0;
  auto alloc = [&](size_t nbytes)->void*{
    off = (off + 255) & ~(size_t)255;
    void* p = ws + off; off += nbytes; return p;
  };
  float* f_es = (float*)alloc((size_t)NN*FF*4);
  float* f_et = (float*)alloc((size_t)NN*FF*4);
  ushort* f_esb = (ushort*)alloc((size_t)NN*FF*2);
  ushort* f_etb = (ushort*)alloc((size_t)NN*FF*2);
  ushort* f_gsb = (ushort*)alloc((size_t)NN*FF*2);
  ushort* f_gtb = (ushort*)alloc((size_t)NN*FF*2);
  ushort* Sb_s = (ushort*)alloc((size_t)NN*FF*2);
  ushort* Sb_t = (ushort*)alloc((size_t)NN*FF*2);
  float* w_s  = (float*)alloc(NN*4);
  float* w_t  = (float*)alloc(NN*4);
  int*   idx_s= (int*)alloc(NN*8*4);
  int*   idx_t= (int*)alloc(NN*8*4);
  float* rmax = (float*)alloc(NN*4);
  float* rmaxp= (float*)alloc((size_t)64*NN*4);
  float* gminp= (float*)alloc((size_t)64*64*4);
  float* stat = (float*)alloc(64);
  float* v    = (float*)alloc((size_t)4*NN*4);
  float* accf = (float*)alloc((size_t)4*NN*4);
  ushort* part = (ushort*)alloc((size_t)4*NCH*NN*2);   // 4 MB
  ushort* Wt0  = (ushort*)alloc((size_t)2*FF*EK*2);    // 4 MB
  off = (off + 255) & ~(size_t)255;
  ushort* stage = (ushort*)(ws + off);         // 32 MB bf16 M0 staging
  uint* K4 = (uint*)(stage + (size_t)NN*NN);   // 32 MB 4-bit, 4 matrices
  // pre-OT overlays:
  ushort* epart = stage;                       // 64 MB bf16 embed partials (stage+K4)
  ushort* Db_s  = stage;                       // 32 MB bf16 raw dot (knn s)
  ushort* Db_t  = (ushort*)K4;                 // 32 MB bf16 raw dot (knn t)

  float* Pout_final = out + 5;
  float* Mout_final = out + 5 + (size_t)NN*NN;

  // ---- embeddings (MFMA split-K=32, both matrices, NT, bf16 partials) ----
  transposeW2<<<dim3(EK/64,2),256,0,stream>>>(W_es, W_et, Wt0);
  embed_mfma2<<<dim3(64,KS,2),256,0,stream>>>(f_s, f_t, Wt0, epart);
  reduce_l2_2<<<dim3(NN,2),128,0,stream>>>(epart, b_es, b_et, f_es, f_et, f_esb, f_etb);

  // ---- knn path: MFMA raw-dot matrices (both in one launch) + weighted select ----
  softmax_rows2<<<dim3(NN,2),128,0,stream>>>(l_s, l_t, Sb_s, Sb_t, w_s, w_t);
  gemm_btb_mfma<<<dim3(64,64,2),256,0,stream>>>(Sb_s, Sb_s, Db_s, Sb_t, Sb_t, Db_t,
                                                nullptr, nullptr);
  knn_select2<<<dim3(NN,2),256,0,stream>>>(Db_s, Db_t, w_s, w_t, idx_s, idx_t);
  encoder_kernel2<<<dim3(NN,2),128,0,stream>>>(f_es, f_et, idx_s, idx_t,
                                               W_gs, W_gt, b_gs, b_gt, f_gsb, f_gtb);

  // ---- OT: per-matrix build (shared stage), then 4-batched sinkhorn ----
  const ushort* ftab[4] = { f_etb, f_gtb, f_etb, f_gtb };
  const ushort* fsab[4] = { f_esb, f_esb, f_gtb, f_gsb };

  vinit4<<<(4*NN+255)/256,256,0,stream>>>(v);
  for (int m=0; m<4; ++m){
    gemm_btb_mfma<<<dim3(64,64,1),256,0,stream>>>(ftab[m], fsab[m], stage,
                                                  ftab[m], fsab[m], stage,
                                                  rmaxp, gminp);
    rowstat2<<<NN/64,256,0,stream>>>(rmaxp, rmax);
    greduce_s<<<1,256,0,stream>>>(rmax, gminp, stat);
    transform_s<<<2048,256,0,stream>>>(stage, K4 + (size_t)m*NN*(NN/8),
        rmax, stat, (m==3) ? Mout_final : (float*)nullptr);
  }
  for (int it=0; it<OT_ITERS; ++it){
    sink_fused<<<dim3(NCH,4),256,0,stream>>>(K4, v, part);
    colfin_b<<<dim3(64,4),256,0,stream>>>(part, v);
  }
  loss2_b<<<dim3(NN,4),256,0,stream>>>(K4, v, accf, Pout_final, 3);
  lossfin_all<<<1,256,0,stream>>>(accf, out);
}

// Round 21
// 874.828 us; speedup vs baseline: 1.0711x; 1.0711x over previous
//
#include <hip/hip_runtime.h>
#include <math.h>

#define NN 4096
#define FF 128
#define CD 100
#define OT_ITERS 20
#define RVAL (1.0f/4096.0f)
#define EK 8192
#define KS 32
#define CHUNK 16
#define NCH 256

typedef unsigned int uint;
typedef unsigned short ushort;
typedef unsigned long long ull;
typedef __attribute__((ext_vector_type(8))) short bf16x8;
typedef __attribute__((ext_vector_type(4))) float f32x4;

// ---------- bf16 helpers ----------
__device__ __forceinline__ float bflo(uint u){ return __uint_as_float(u << 16); }
__device__ __forceinline__ float bfhi(uint u){ return __uint_as_float(u & 0xFFFF0000u); }
__device__ __forceinline__ float bf2f(ushort s){ return __uint_as_float((uint)s << 16); }
__device__ __forceinline__ ushort f2bf(float x){
  uint u = __float_as_uint(x);
  u += 0x7FFFu + ((u >> 16) & 1u);
  return (ushort)(u >> 16);
}
__device__ __forceinline__ void unpack8(uint4 kk, float* e){
  e[0]=bflo(kk.x); e[1]=bfhi(kk.x); e[2]=bflo(kk.y); e[3]=bfhi(kk.y);
  e[4]=bflo(kk.z); e[5]=bfhi(kk.z); e[6]=bflo(kk.w); e[7]=bfhi(kk.w);
}
__device__ __forceinline__ uint4 pack8(const float* e){
  union { ushort us[8]; uint4 u4; } pk;
#pragma unroll
  for (int k=0;k<8;++k) pk.us[k]=f2bf(e[k]);
  return pk.u4;
}

// ---------- 4-bit linear codec: K in [e^-1, 1]; K = A4 + B4*n ----------
#define A4 0.36787944f
#define B4 0.042141372f
#define INVB4 23.729603f
__device__ __forceinline__ uint e4(float f){
  float q = (f - A4) * INVB4;
  int n = (int)(q + 0.5f);
  n = n < 0 ? 0 : (n > 15 ? 15 : n);
  return (uint)n;
}
__device__ __forceinline__ void d4x8(uint w, float* e){
#pragma unroll
  for (int k=0;k<8;++k)
    e[k] = A4 + B4 * (float)((w >> (4*k)) & 15u);
}

// ---------- wave/block reduce helpers (wave = 64) ----------
__device__ __forceinline__ float waveSum(float v){
#pragma unroll
  for (int o=32;o>0;o>>=1) v += __shfl_down(v,o);
  return v;
}
__device__ __forceinline__ float waveMax(float v){
#pragma unroll
  for (int o=32;o>0;o>>=1) v = fmaxf(v,__shfl_down(v,o));
  return v;
}
__device__ __forceinline__ float waveMin(float v){
#pragma unroll
  for (int o=32;o>0;o>>=1) v = fminf(v,__shfl_down(v,o));
  return v;
}
__device__ __forceinline__ float blkSum(float v, float* red){
  v = waveSum(v);
  if ((threadIdx.x&63)==0) red[threadIdx.x>>6] = v;
  __syncthreads();
  float r = red[0]+red[1]+red[2]+red[3];
  __syncthreads();
  return r;
}

// ---------- W transpose+convert (both weights): Wt[z][n][k] bf16 ----------
__global__ __launch_bounds__(256) void transposeW2(const float* __restrict__ W0,
                                                   const float* __restrict__ W1,
                                                   ushort* __restrict__ Wtb)
{
  __shared__ ushort T[128][72];
  const int z = blockIdx.y;
  const float* W = z ? W1 : W0;
  ushort* Wt = Wtb + (size_t)z*FF*EK;
  const int k0 = blockIdx.x*64, tid = threadIdx.x;
#pragma unroll
  for (int it=0; it<8; ++it){
    int f = tid + it*256;
    int r = f >> 5, c4 = f & 31;
    float4 v = *(const float4*)&W[(size_t)(k0+r)*FF + c4*4];
    T[c4*4+0][r]=f2bf(v.x); T[c4*4+1][r]=f2bf(v.y);
    T[c4*4+2][r]=f2bf(v.z); T[c4*4+3][r]=f2bf(v.w);
  }
  __syncthreads();
#pragma unroll
  for (int it=0; it<4; ++it){
    int f = tid + it*256;
    int n = f >> 3, c8 = f & 7;
    *(uint4*)&Wt[(size_t)n*EK + k0 + c8*8] = *(uint4*)&T[n][c8*8];
  }
}

// ---------- MFMA embed GEMM, both matrices, split-K=32, NT, bf16 partials ----------
__global__ __launch_bounds__(256) void embed_mfma2(const float* __restrict__ A0,
                                                   const float* __restrict__ A1,
                                                   const ushort* __restrict__ Wtb,
                                                   ushort* __restrict__ partb)
{
  __shared__ char smem[64*72*2 + 128*72*2];
  ushort (*Al)[72] = (ushort(*)[72])smem;
  ushort (*Wl)[72] = (ushort(*)[72])(smem + 64*72*2);
  float  (*Cst)[130] = (float(*)[130])smem;

  const int tid = threadIdx.x;
  const int z = blockIdx.z;
  const float* A = z ? A1 : A0;
  const ushort* Wt = Wtb + (size_t)z*FF*EK;
  ushort* part = partb + (size_t)z*KS*NN*FF;
  const int m0 = blockIdx.x * 64;
  const int kc = blockIdx.y * (EK/KS);
  const int w = tid >> 6, l = tid & 63;
  const int wr = w >> 1, wc = w & 1;
  const int lrow = l & 15, lk = (l >> 4) * 8;
  f32x4 acc[2][4];
#pragma unroll
  for (int mi=0;mi<2;++mi)
#pragma unroll
    for (int ni=0;ni<4;++ni) acc[mi][ni] = (f32x4){0.f,0.f,0.f,0.f};

  f32x4 aReg[4];
  uint4  wReg[4];
  auto gload = [&](int k0){
#pragma unroll
    for (int it=0;it<4;++it){
      int f = tid + it*256;
      int r = f >> 4, c4 = f & 15;
      aReg[it] = __builtin_nontemporal_load((const f32x4*)&A[(size_t)(m0+r)*EK + k0 + c4*4]);
    }
#pragma unroll
    for (int it=0;it<4;++it){
      int f = tid + it*256;
      int r = f >> 3, c8 = f & 7;
      wReg[it] = *(const uint4*)&Wt[(size_t)r*EK + k0 + c8*8];
    }
  };

  const int NSTEP = (EK/KS)/64;
  gload(kc);
  for (int step=0; step<NSTEP; ++step){
    __syncthreads();
#pragma unroll
    for (int it=0;it<4;++it){
      int f = tid + it*256;
      int r = f >> 4, c4 = f & 15;
      f32x4 a4 = aReg[it];
      union { ushort us[4]; uint2 u2; } pk;
      pk.us[0]=f2bf(a4[0]); pk.us[1]=f2bf(a4[1]); pk.us[2]=f2bf(a4[2]); pk.us[3]=f2bf(a4[3]);
      *(uint2*)&Al[r][c4*4] = pk.u2;
    }
#pragma unroll
    for (int it=0;it<4;++it){
      int f = tid + it*256;
      int r = f >> 3, c8 = f & 7;
      *(uint4*)&Wl[r][c8*8] = wReg[it];
    }
    __syncthreads();
    if (step+1 < NSTEP) gload(kc + (step+1)*64);
#pragma unroll
    for (int ksub = 0; ksub < 2; ++ksub) {
      bf16x8 af[2], bfr[4];
#pragma unroll
      for (int mi=0;mi<2;++mi) af[mi] = *(bf16x8*)&Al[wr*32+mi*16+lrow][ksub*32+lk];
#pragma unroll
      for (int ni=0;ni<4;++ni) bfr[ni] = *(bf16x8*)&Wl[wc*64+ni*16+lrow][ksub*32+lk];
#pragma unroll
      for (int mi=0;mi<2;++mi)
#pragma unroll
        for (int ni=0;ni<4;++ni)
          acc[mi][ni] = __builtin_amdgcn_mfma_f32_16x16x32_bf16(af[mi], bfr[ni], acc[mi][ni], 0,0,0);
    }
  }
  // ---- coalesced epilogue: stage fp32 in LDS, store bf16 NT (ull) ----
#pragma unroll
  for (int half=0; half<2; ++half){
    __syncthreads();
    if (wr == half){
#pragma unroll
      for (int mi=0;mi<2;++mi)
#pragma unroll
        for (int ni=0;ni<4;++ni)
#pragma unroll
          for (int r=0;r<4;++r){
            int rr = mi*16 + (l>>4)*4 + r;
            int col = wc*64 + ni*16 + lrow;
            Cst[rr][col] = acc[mi][ni][r];
          }
    }
    __syncthreads();
#pragma unroll
    for (int it=0;it<4;++it){
      int f = tid + it*256;
      int rr = f >> 5, g = f & 31;
      float4 o = *(float4*)&Cst[rr][g*4];
      union { ushort us[4]; ull u8; } pk;
      pk.us[0]=f2bf(o.x); pk.us[1]=f2bf(o.y); pk.us[2]=f2bf(o.z); pk.us[3]=f2bf(o.w);
      __builtin_nontemporal_store(pk.u8,
        (ull*)&part[((size_t)blockIdx.y*NN + m0 + half*32 + rr)*FF + g*4]);
    }
  }
}

// ---------- reduce bf16 split-K partials + bias + l2norm, both matrices ----------
__global__ __launch_bounds__(128) void reduce_l2_2(const ushort* __restrict__ partb,
                                                   const float* __restrict__ b0,
                                                   const float* __restrict__ b1,
                                                   float* __restrict__ o0,
                                                   float* __restrict__ o1,
                                                   ushort* __restrict__ ob0,
                                                   ushort* __restrict__ ob1)
{
  __shared__ float red[2];
  const int z = blockIdx.y;
  const ushort* part = partb + (size_t)z*KS*NN*FF;
  const float* bias = z ? b1 : b0;
  float* out = z ? o1 : o0;
  ushort* outb = z ? ob1 : ob0;
  int i = blockIdx.x, t = threadIdx.x;
  float s = bias[t];
#pragma unroll
  for (int ks=0; ks<KS; ++ks) s += bf2f(part[((size_t)ks*NN + i)*FF + t]);
  float q = waveSum(s*s);
  if ((t&63)==0) red[t>>6]=q;
  __syncthreads();
  float val = s / sqrtf(red[0]+red[1]);
  out[(size_t)i*FF+t] = val;
  outb[(size_t)i*FF+t] = f2bf(val);
}

// ---------- softmax rows (both): Sb bf16 [4096][128] padded, w = ||S_row|| ----------
__global__ __launch_bounds__(128) void softmax_rows2(const float* __restrict__ l0,
                                                     const float* __restrict__ l1,
                                                     ushort* __restrict__ Sb0,
                                                     ushort* __restrict__ Sb1,
                                                     float* __restrict__ w0,
                                                     float* __restrict__ w1)
{
  __shared__ float sm[2], ss[2], sq[2];
  const int z = blockIdx.y;
  const float* l = z ? l1 : l0;
  ushort* Sb = z ? Sb1 : Sb0;
  float* w = z ? w1 : w0;
  int i = blockIdx.x, t = threadIdx.x;
  int lane = t & 63, wid = t >> 6;
  float x = (t < CD) ? l[(size_t)i*CD + t] : -3.4e38f;
  float m = waveMax(x);
  if (lane==0) sm[wid]=m;
  __syncthreads();
  m = fmaxf(sm[0], sm[1]);
  float e = (t < CD) ? __expf(x - m) : 0.f;
  float s = waveSum(e);
  if (lane==0) ss[wid]=s;
  __syncthreads();
  float tot = ss[0]+ss[1];
  float sv = e / tot;
  Sb[(size_t)i*FF + t] = (t < CD) ? f2bf(sv) : (ushort)0;
  float q = waveSum(sv*sv);
  if (lane==0) sq[wid]=q;
  __syncthreads();
  if (t==0) w[i] = sqrtf(sq[0]+sq[1]);
}

// ---------- top-7 select from raw bf16 dot matrix, both matrices ----------
__global__ __launch_bounds__(256) void knn_select2(const ushort* __restrict__ Ds,
                                                   const ushort* __restrict__ Dt,
                                                   const float* __restrict__ w_s,
                                                   const float* __restrict__ w_t,
                                                   int* __restrict__ idx_s,
                                                   int* __restrict__ idx_t)
{
  __shared__ float redv[256];
  __shared__ int   redi[256];
  const int z = blockIdx.y;
  const ushort* D = z ? Dt : Ds;
  const float* w = z ? w_t : w_s;
  int* idx = z ? idx_t : idx_s;
  int i = blockIdx.x, tid = threadIdx.x;
  float wi = w[i];
  float bv[7]; int bi[7];
#pragma unroll
  for (int m=0;m<7;++m){ bv[m]=-3.4e38f; bi[m]=-1; }
  const uint4* row4 = (const uint4*)&D[(size_t)i*NN];
#pragma unroll
  for (int ss=0;ss<2;++ss){
    int j8 = tid + ss*256;
    float e[8]; unpack8(row4[j8], e);
#pragma unroll
    for (int q=0;q<8;++q){
      int j = j8*8 + q;
      float cv = e[q] / fmaxf(wi * w[j], 1e-7f);
      cv = (j==i) ? -3.4e38f : cv;
      if (cv > bv[6]) {
        int m = 6;
        while (m > 0 && cv > bv[m-1]) { bv[m]=bv[m-1]; bi[m]=bi[m-1]; --m; }
        bv[m]=cv; bi[m]=j;
      }
    }
  }
  if (tid==0) idx[(size_t)i*8] = i;
  for (int m=0;m<7;++m) {
    redv[tid]=bv[0]; redi[tid]=tid;
    __syncthreads();
    for (int s=128;s>=1;s>>=1) {
      if (tid < s) {
        if (redv[tid+s] > redv[tid]) { redv[tid]=redv[tid+s]; redi[tid]=redi[tid+s]; }
      }
      __syncthreads();
    }
    int wt = redi[0];
    if (tid == wt) {
      idx[(size_t)i*8 + 1 + m] = bi[0];
#pragma unroll
      for (int q=0;q<6;++q){ bv[q]=bv[q+1]; bi[q]=bi[q+1]; }
      bv[6]=-3.4e38f; bi[6]=-1;
    }
    __syncthreads();
  }
}

// ---------- encoder (both): outb = bf16(l2norm(concat(h, mean(h[idx])) @ W + b)) ----------
__global__ __launch_bounds__(128) void encoder_kernel2(const float* __restrict__ h0,
                                                       const float* __restrict__ h1,
                                                       const int* __restrict__ idx0,
                                                       const int* __restrict__ idx1,
                                                       const float* __restrict__ W0,
                                                       const float* __restrict__ W1,
                                                       const float* __restrict__ bb0,
                                                       const float* __restrict__ bb1,
                                                       ushort* __restrict__ o0,
                                                       ushort* __restrict__ o1)
{
  __shared__ float hin[256];
  __shared__ float sred[2];
  const int z = blockIdx.y;
  const float* h = z ? h1 : h0;
  const int* idx = z ? idx1 : idx0;
  const float* W = z ? W1 : W0;
  const float* bias = z ? bb1 : bb0;
  ushort* outb = z ? o1 : o0;
  int i = blockIdx.x, t = threadIdx.x;
  float hv = h[(size_t)i*FF + t];
  float agg = 0.f;
#pragma unroll
  for (int m=0;m<8;++m) agg += h[(size_t)idx[i*8+m]*FF + t];
  agg *= 0.125f;
  hin[t] = hv; hin[FF + t] = agg;
  __syncthreads();
  float acc = bias[t];
  for (int k=0;k<256;++k) acc += hin[k] * W[(size_t)k*FF + t];
  float s = waveSum(acc*acc);
  int lane = t & 63, wid = t >> 6;
  if (lane==0) sred[wid]=s;
  __syncthreads();
  float tot = sred[0]+sred[1];
  outb[(size_t)i*FF + t] = f2bf(acc / sqrtf(tot));
}

// ---------- MFMA: C bf16 = A bf16 @ B^T, z-select inputs, optional stats ----------
__global__ __launch_bounds__(256) void gemm_btb_mfma(const ushort* __restrict__ A0,
                                                     const ushort* __restrict__ B0,
                                                     ushort* __restrict__ C0,
                                                     const ushort* __restrict__ A1,
                                                     const ushort* __restrict__ B1,
                                                     ushort* __restrict__ C1,
                                                     float* __restrict__ rmaxp,
                                                     float* __restrict__ gminp)
{
  __shared__ ushort Al[64][136];
  __shared__ ushort Bl[64][136];
  __shared__ float rmx2[64][2];
  __shared__ float gmnw[4];
  const int z = blockIdx.z;
  const ushort* A = z ? A1 : A0;
  const ushort* B = z ? B1 : B0;
  ushort* C = z ? C1 : C0;
  const int tid = threadIdx.x;
  const int i0 = blockIdx.y*64, j0 = blockIdx.x*64;
#pragma unroll
  for (int it=0; it<4; ++it){
    int f = tid + it*256;
    int r = f >> 4, c8 = f & 15;
    *(uint4*)&Al[r][c8*8] = *(const uint4*)&A[(size_t)(i0+r)*FF + c8*8];
    *(uint4*)&Bl[r][c8*8] = *(const uint4*)&B[(size_t)(j0+r)*FF + c8*8];
  }
  __syncthreads();
  const int w = tid>>6, l = tid&63;
  const int wr = w>>1, wc = w&1;
  const int lrow = l&15, lk = (l>>4)*8;
  f32x4 acc[2][2];
#pragma unroll
  for (int mi=0;mi<2;++mi)
#pragma unroll
    for (int ni=0;ni<2;++ni) acc[mi][ni] = (f32x4){0.f,0.f,0.f,0.f};
#pragma unroll
  for (int ks=0; ks<4; ++ks){
    bf16x8 af[2], bfm[2];
#pragma unroll
    for (int mi=0;mi<2;++mi) af[mi] = *(bf16x8*)&Al[wr*32+mi*16+lrow][ks*32+lk];
#pragma unroll
    for (int ni=0;ni<2;++ni) bfm[ni] = *(bf16x8*)&Bl[wc*32+ni*16+lrow][ks*32+lk];
#pragma unroll
    for (int mi=0;mi<2;++mi)
#pragma unroll
      for (int ni=0;ni<2;++ni)
        acc[mi][ni] = __builtin_amdgcn_mfma_f32_16x16x32_bf16(af[mi], bfm[ni], acc[mi][ni], 0,0,0);
  }
  if (rmaxp){
    float rowm[8]; float gmn = 3.4e38f;
#pragma unroll
    for (int mi=0;mi<2;++mi)
#pragma unroll
      for (int r=0;r<4;++r){
        float a = fmaxf(acc[mi][0][r], acc[mi][1][r]);
        float c = fminf(acc[mi][0][r], acc[mi][1][r]);
        rowm[mi*4+r] = a;
        gmn = fminf(gmn, c);
      }
#pragma unroll
    for (int mo=1; mo<16; mo<<=1){
#pragma unroll
      for (int q=0;q<8;++q) rowm[q] = fmaxf(rowm[q], __shfl_xor(rowm[q], mo));
      gmn = fminf(gmn, __shfl_xor(gmn, mo));
    }
    if (lrow == 0){
#pragma unroll
      for (int mi=0;mi<2;++mi)
#pragma unroll
        for (int r=0;r<4;++r)
          rmx2[wr*32 + mi*16 + (l>>4)*4 + r][wc] = rowm[mi*4+r];
    }
    gmn = fminf(gmn, __shfl_xor(gmn, 16));
    gmn = fminf(gmn, __shfl_xor(gmn, 32));
    if (l==0) gmnw[w] = gmn;
    __syncthreads();
    if (tid < 64)
      rmaxp[(size_t)blockIdx.x*NN + i0 + tid] = fmaxf(rmx2[tid][0], rmx2[tid][1]);
    if (tid == 0)
      gminp[blockIdx.y*64 + blockIdx.x] = fminf(fminf(gmnw[0],gmnw[1]),fminf(gmnw[2],gmnw[3]));
  }
  __syncthreads();
  ushort (*Cl)[72] = (ushort(*)[72])&Al[0][0];
#pragma unroll
  for (int mi=0;mi<2;++mi)
#pragma unroll
    for (int ni=0;ni<2;++ni)
#pragma unroll
      for (int r=0;r<4;++r){
        int row = wr*32 + mi*16 + (l>>4)*4 + r;
        int col = wc*32 + ni*16 + lrow;
        Cl[row][col] = f2bf(acc[mi][ni][r]);
      }
  __syncthreads();
#pragma unroll
  for (int it=0; it<2; ++it){
    int f = tid + it*256;
    int r = f >> 3, c8 = f & 7;
    *(uint4*)&C[(size_t)(i0+r)*NN + j0 + c8*8] = *(uint4*)&Cl[r][c8*8];
  }
}

// ---------- rowmax finalize: 4 threads per row (64 blocks) ----------
__global__ __launch_bounds__(256) void rowstat2(const float* __restrict__ rmaxp,
                                                float* __restrict__ rmax)
{
  int t = threadIdx.x;
  int row = blockIdx.x*64 + (t >> 2);
  int q = t & 3;
  float m = -3.4e38f;
#pragma unroll
  for (int b=0;b<16;++b) m = fmaxf(m, rmaxp[(size_t)(q*16+b)*NN + row]);
  m = fmaxf(m, __shfl_xor(m, 1));
  m = fmaxf(m, __shfl_xor(m, 2));
  if (q==0) rmax[row] = m;
}

// ---------- stat finalize: stat = {gmin, 1/(gmax-gmin)} ----------
__global__ __launch_bounds__(256) void greduce_s(const float* __restrict__ rmax,
                                                 const float* __restrict__ gminp,
                                                 float* __restrict__ stat)
{
  __shared__ float r1[4], r2[4];
  int t = threadIdx.x;
  float mx=-3.4e38f, mn=3.4e38f;
  for (int i=t; i<NN; i+=256){
    mx = fmaxf(mx, rmax[i]);
    mn = fminf(mn, gminp[i]);
  }
  mx = waveMax(mx); mn = waveMin(mn);
  int lane = t & 63, wid = t >> 6;
  if (lane==0){ r1[wid]=mx; r2[wid]=mn; }
  __syncthreads();
  if (t==0){
    float gmx = fmaxf(fmaxf(r1[0],r1[1]),fmaxf(r1[2],r1[3]));
    float gmn = fminf(fminf(r2[0],r2[1]),fminf(r2[2],r2[3]));
    stat[0] = gmn;
    stat[1] = 1.f/(gmx-gmn);
  }
}

// ---------- single-matrix: K4 = 4bit(exp((M0 - rowmax)*scale)); optional M out ----------
__global__ __launch_bounds__(256) void transform_s(const ushort* __restrict__ stage,
                                                   uint* __restrict__ K4m,
                                                   const float* __restrict__ rmax,
                                                   const float* __restrict__ stat,
                                                   float* __restrict__ Mout)
{
  const float gmin = stat[0], scale = stat[1];
  const uint4* Km = (const uint4*)stage;
  const bool wM = (Mout != nullptr);
  const int total8 = (NN*NN)/8;
  for (int f = blockIdx.x*256 + threadIdx.x; f < total8; f += gridDim.x*256){
    int i = f >> 9;
    float rm = rmax[i];
    float e[8]; unpack8(Km[f], e);
    uint o = 0;
#pragma unroll
    for (int k=0;k<8;++k) o |= e4(__expf((e[k]-rm)*scale)) << (4*k);
    K4m[f] = o;
    if (wM){
      float4 o1, o2;
      o1.x=(e[0]-gmin)*scale; o1.y=(e[1]-gmin)*scale; o1.z=(e[2]-gmin)*scale; o1.w=(e[3]-gmin)*scale;
      o2.x=(e[4]-gmin)*scale; o2.y=(e[5]-gmin)*scale; o2.z=(e[6]-gmin)*scale; o2.w=(e[7]-gmin)*scale;
      float4* mp = (float4*)(Mout + (size_t)f*8);
      mp[0]=o1; mp[1]=o2;
    }
  }
}

// ---------- init: v=1 for all 4 matrices ----------
__global__ void vinit4(float* __restrict__ v)
{
  int g = blockIdx.x*256 + threadIdx.x;
  if (g < 4*NN) v[g] = 1.f;
}

// ---------- fused sinkhorn iteration over 4-bit K, paired-row barriers ----------
__global__ __launch_bounds__(256) void sink_fused(const uint* __restrict__ K4base,
                                                  const float* __restrict__ vv,
                                                  ushort* __restrict__ part)
{
  __shared__ float red2[2][4];
  const int m = blockIdx.y, b = blockIdx.x, t = threadIdx.x;
  const int i0 = b*CHUNK;
  const uint* K4 = K4base + (size_t)m*NN*(NN/8);
  const float4* v4 = (const float4*)(vv + (size_t)m*NN);
  const int lane = t & 63, wid = t >> 6;
  float vs[16];
  {
    float4 A=v4[t*4+0], B=v4[t*4+1], C=v4[t*4+2], D=v4[t*4+3];
    vs[0]=A.x; vs[1]=A.y; vs[2]=A.z; vs[3]=A.w;
    vs[4]=B.x; vs[5]=B.y; vs[6]=B.z; vs[7]=B.w;
    vs[8]=C.x; vs[9]=C.y; vs[10]=C.z; vs[11]=C.w;
    vs[12]=D.x; vs[13]=D.y; vs[14]=D.z; vs[15]=D.w;
  }
  float vsum = 0.f;
#pragma unroll
  for (int k=0;k<16;++k) vsum += vs[k];
  float colacc[16];
#pragma unroll
  for (int k=0;k<16;++k) colacc[k]=0.f;
  for (int r=0;r<CHUNK;r+=2){
    uint2 kw0 = ((const uint2*)(K4 + (size_t)(i0+r  )*(NN/8)))[t];
    uint2 kw1 = ((const uint2*)(K4 + (size_t)(i0+r+1)*(NN/8)))[t];
    float s0 = 0.f, s1 = 0.f;
#pragma unroll
    for (int k=0;k<8;++k){
      s0 += (float)((kw0.x >> (4*k)) & 15u) * vs[k];
      s0 += (float)((kw0.y >> (4*k)) & 15u) * vs[k+8];
      s1 += (float)((kw1.x >> (4*k)) & 15u) * vs[k];
      s1 += (float)((kw1.y >> (4*k)) & 15u) * vs[k+8];
    }
    float d0 = waveSum(A4*vsum + B4*s0);
    float d1 = waveSum(A4*vsum + B4*s1);
    if (lane==0){ red2[0][wid]=d0; red2[1][wid]=d1; }
    __syncthreads();
    float ur0 = RVAL / (red2[0][0]+red2[0][1]+red2[0][2]+red2[0][3]);
    float ur1 = RVAL / (red2[1][0]+red2[1][1]+red2[1][2]+red2[1][3]);
    __syncthreads();
    const float a0 = A4*ur0 + A4*ur1;
    const float b0 = B4*ur0, b1 = B4*ur1;
#pragma unroll
    for (int k=0;k<8;++k){
      colacc[k]   += a0 + b0*(float)((kw0.x >> (4*k)) & 15u) + b1*(float)((kw1.x >> (4*k)) & 15u);
      colacc[k+8] += a0 + b0*(float)((kw0.y >> (4*k)) & 15u) + b1*(float)((kw1.y >> (4*k)) & 15u);
    }
  }
  ushort* prow = part + ((size_t)m*NCH + b)*NN;
  ((uint4*)prow)[t*2]   = pack8(colacc);
  ((uint4*)prow)[t*2+1] = pack8(colacc+8);
}

// ---------- column finish: v[j] = R / sum_b part[m][b][j]; 64 cols/block ----------
__global__ __launch_bounds__(256) void colfin_b(const ushort* __restrict__ part,
                                                float* __restrict__ vv)
{
  __shared__ float lds[32][8][9];
  const int m = blockIdx.y, bx = blockIdx.x, t = threadIdx.x;
  const int g = t & 7;
  const int tq = t >> 3;
  const uint4* pb = (const uint4*)(part + (size_t)m*NCH*NN);
  float acc[8];
#pragma unroll
  for (int k=0;k<8;++k) acc[k]=0.f;
#pragma unroll
  for (int s=0;s<8;++s){
    int b = tq + s*32;
    float e[8]; unpack8(pb[(size_t)b*512 + bx*8 + g], e);
#pragma unroll
    for (int k=0;k<8;++k) acc[k] += e[k];
  }
#pragma unroll
  for (int k=0;k<8;++k) lds[tq][g][k] = acc[k];
  __syncthreads();
  if (t < 64){
    int gg = t >> 3, c = t & 7;
    float s = 0.f;
#pragma unroll
    for (int q=0;q<32;++q) s += lds[q][gg][c];
    vv[(size_t)m*NN + bx*64 + gg*8 + c] = RVAL / s;
  }
}

// ---------- final: y = Kv ; P = K v_j / y ; per-row loss partial ----------
__global__ __launch_bounds__(256) void loss2_b(const uint* __restrict__ K4base,
                                               const float* __restrict__ vv,
                                               float* __restrict__ accf,
                                               float* __restrict__ Pout, int finalm)
{
  __shared__ float red[4];
  int m = blockIdx.y, i = blockIdx.x, t = threadIdx.x;
  const uint2* row = (const uint2*)(K4base + ((size_t)m*NN + i)*(NN/8));
  const float4* v4 = (const float4*)(vv + (size_t)m*NN);
  uint2 kw = row[t];
  float e[16];
  d4x8(kw.x, e); d4x8(kw.y, e+8);
  float vr[16];
  {
    float4 A=v4[t*4+0], B=v4[t*4+1], C=v4[t*4+2], D=v4[t*4+3];
    vr[0]=A.x; vr[1]=A.y; vr[2]=A.z; vr[3]=A.w;
    vr[4]=B.x; vr[5]=B.y; vr[6]=B.z; vr[7]=B.w;
    vr[8]=C.x; vr[9]=C.y; vr[10]=C.z; vr[11]=C.w;
    vr[12]=D.x; vr[13]=D.y; vr[14]=D.z; vr[15]=D.w;
  }
  float s = 0.f;
#pragma unroll
  for (int k=0;k<16;++k) s += e[k]*vr[k];
  float y = blkSum(s, red);
  float invy = 1.f / y;
  const bool wp = (m==finalm) && (Pout != nullptr);
  const int j0 = t*16;
  float p[16];
#pragma unroll
  for (int k=0;k<16;++k) p[k] = e[k]*vr[k]*invy;
  if (wp){
    float4* pp = (float4*)(Pout + (size_t)i*NN + j0);
#pragma unroll
    for (int q=0;q<4;++q){
      float4 o; o.x=p[q*4]; o.y=p[q*4+1]; o.z=p[q*4+2]; o.w=p[q*4+3];
      pp[q]=o;
    }
  }
  float local = 0.f;
#pragma unroll
  for (int k=0;k<16;++k){
    float d = p[k] - ((j0+k)==i ? 1.f : 0.f);
    local += d*d;
  }
  float tot = blkSum(local, red);
  if (t==0) accf[(size_t)m*NN + i] = tot;
}

// ---------- all four losses + total in one kernel ----------
__global__ __launch_bounds__(256) void lossfin_all(const float* __restrict__ accf,
                                                   float* __restrict__ out)
{
  __shared__ float red[4];
  int t = threadIdx.x;
  float L[4];
#pragma unroll
  for (int m=0;m<4;++m){
    float s = 0.f;
#pragma unroll
    for (int q=0;q<16;++q) s += accf[(size_t)m*NN + t + q*256];
    float tot = blkSum(s, red);
    L[m] = sqrtf(tot);
  }
  if (t==0){
    out[1]=L[0]; out[3]=L[1]; out[4]=L[2]; out[2]=L[3];
    out[0]=L[0]+L[1]+L[2]+L[3];
  }
}

extern "C" void kernel_launch(void* const* d_in, const int* in_sizes, int n_in,
                              void* d_out, int out_size, void* d_ws, size_t ws_size,
                              hipStream_t stream)
{
  (void)in_sizes; (void)n_in; (void)out_size; (void)ws_size;
  const float* f_s  = (const float*)d_in[1];
  const float* l_s  = (const float*)d_in[2];
  const float* f_t  = (const float*)d_in[3];
  const float* l_t  = (const float*)d_in[4];
  const float* W_es = (const float*)d_in[5];
  const float* b_es = (const float*)d_in[6];
  const float* W_et = (const float*)d_in[7];
  const float* b_et = (const float*)d_in[8];
  const float* W_gs = (const float*)d_in[9];
  const float* b_gs = (const float*)d_in[10];
  const float* W_gt = (const float*)d_in[11];
  const float* b_gt = (const float*)d_in[12];
  float* out = (float*)d_out;

  char* ws = (char*)d_ws;
  size_t off = 0;
  auto alloc = [&](size_t nbytes)->void*{
    off = (off + 255) & ~(size_t)255;
    void* p = ws + off; off += nbytes; return p;
  };
  float* f_es = (float*)alloc((size_t)NN*FF*4);
  float* f_et = (float*)alloc((size_t)NN*FF*4);
  ushort* f_esb = (ushort*)alloc((size_t)NN*FF*2);
  ushort* f_etb = (ushort*)alloc((size_t)NN*FF*2);
  ushort* f_gsb = (ushort*)alloc((size_t)NN*FF*2);
  ushort* f_gtb = (ushort*)alloc((size_t)NN*FF*2);
  ushort* Sb_s = (ushort*)alloc((size_t)NN*FF*2);
  ushort* Sb_t = (ushort*)alloc((size_t)NN*FF*2);
  float* w_s  = (float*)alloc(NN*4);
  float* w_t  = (float*)alloc(NN*4);
  int*   idx_s= (int*)alloc(NN*8*4);
  int*   idx_t= (int*)alloc(NN*8*4);
  float* rmax = (float*)alloc(NN*4);
  float* rmaxp= (float*)alloc((size_t)64*NN*4);
  float* gminp= (float*)alloc((size_t)64*64*4);
  float* stat = (float*)alloc(64);
  float* v    = (float*)alloc((size_t)4*NN*4);
  float* accf = (float*)alloc((size_t)4*NN*4);
  ushort* part = (ushort*)alloc((size_t)4*NCH*NN*2);   // 8 MB
  ushort* Wt0  = (ushort*)alloc((size_t)2*FF*EK*2);    // 4 MB
  off = (off + 255) & ~(size_t)255;
  ushort* stage = (ushort*)(ws + off);         // 32 MB bf16 M0 staging
  uint* K4 = (uint*)(stage + (size_t)NN*NN);   // 32 MB 4-bit, 4 matrices
  // pre-OT overlays:
  ushort* epart = stage;                       // 64 MB bf16 embed partials (stage+K4)
  ushort* Db_s  = stage;                       // 32 MB bf16 raw dot (knn s)
  ushort* Db_t  = (ushort*)K4;                 // 32 MB bf16 raw dot (knn t)

  float* Pout_final = out + 5;
  float* Mout_final = out + 5 + (size_t)NN*NN;

  // ---- embeddings (MFMA split-K=32, both matrices, NT, bf16 partials) ----
  transposeW2<<<dim3(EK/64,2),256,0,stream>>>(W_es, W_et, Wt0);
  embed_mfma2<<<dim3(64,KS,2),256,0,stream>>>(f_s, f_t, Wt0, epart);
  reduce_l2_2<<<dim3(NN,2),128,0,stream>>>(epart, b_es, b_et, f_es, f_et, f_esb, f_etb);

  // ---- knn path: MFMA raw-dot matrices (both in one launch) + weighted select ----
  softmax_rows2<<<dim3(NN,2),128,0,stream>>>(l_s, l_t, Sb_s, Sb_t, w_s, w_t);
  gemm_btb_mfma<<<dim3(64,64,2),256,0,stream>>>(Sb_s, Sb_s, Db_s, Sb_t, Sb_t, Db_t,
                                                nullptr, nullptr);
  knn_select2<<<dim3(NN,2),256,0,stream>>>(Db_s, Db_t, w_s, w_t, idx_s, idx_t);
  encoder_kernel2<<<dim3(NN,2),128,0,stream>>>(f_es, f_et, idx_s, idx_t,
                                               W_gs, W_gt, b_gs, b_gt, f_gsb, f_gtb);

  // ---- OT: per-matrix build (shared stage), then 4-batched sinkhorn ----
  const ushort* ftab[4] = { f_etb, f_gtb, f_etb, f_gtb };
  const ushort* fsab[4] = { f_esb, f_esb, f_gtb, f_gsb };

  vinit4<<<(4*NN+255)/256,256,0,stream>>>(v);
  for (int m=0; m<4; ++m){
    gemm_btb_mfma<<<dim3(64,64,1),256,0,stream>>>(ftab[m], fsab[m], stage,
                                                  ftab[m], fsab[m], stage,
                                                  rmaxp, gminp);
    rowstat2<<<NN/64,256,0,stream>>>(rmaxp, rmax);
    greduce_s<<<1,256,0,stream>>>(rmax, gminp, stat);
    transform_s<<<2048,256,0,stream>>>(stage, K4 + (size_t)m*NN*(NN/8),
        rmax, stat, (m==3) ? Mout_final : (float*)nullptr);
  }
  for (int it=0; it<OT_ITERS; ++it){
    sink_fused<<<dim3(NCH,4),256,0,stream>>>(K4, v, part);
    colfin_b<<<dim3(64,4),256,0,stream>>>(part, v);
  }
  loss2_b<<<dim3(NN,4),256,0,stream>>>(K4, v, accf, Pout_final, 3);
  lossfin_all<<<1,256,0,stream>>>(accf, out);
}

// Round 22
// 845.836 us; speedup vs baseline: 1.1078x; 1.0343x over previous
//
#include <hip/hip_runtime.h>
#include <math.h>

#define NN 4096
#define FF 128
#define CD 100
#define OT_ITERS 20
#define RVAL (1.0f/4096.0f)
#define EK 8192
#define KS 32
#define CHUNK 16
#define NCH 256

typedef unsigned int uint;
typedef unsigned short ushort;
typedef unsigned long long ull;
typedef __attribute__((ext_vector_type(8))) short bf16x8;
typedef __attribute__((ext_vector_type(4))) float f32x4;

// ---------- bf16 helpers ----------
__device__ __forceinline__ float bflo(uint u){ return __uint_as_float(u << 16); }
__device__ __forceinline__ float bfhi(uint u){ return __uint_as_float(u & 0xFFFF0000u); }
__device__ __forceinline__ float bf2f(ushort s){ return __uint_as_float((uint)s << 16); }
__device__ __forceinline__ ushort f2bf(float x){
  uint u = __float_as_uint(x);
  u += 0x7FFFu + ((u >> 16) & 1u);
  return (ushort)(u >> 16);
}
__device__ __forceinline__ void unpack8(uint4 kk, float* e){
  e[0]=bflo(kk.x); e[1]=bfhi(kk.x); e[2]=bflo(kk.y); e[3]=bfhi(kk.y);
  e[4]=bflo(kk.z); e[5]=bfhi(kk.z); e[6]=bflo(kk.w); e[7]=bfhi(kk.w);
}
__device__ __forceinline__ uint4 pack8(const float* e){
  union { ushort us[8]; uint4 u4; } pk;
#pragma unroll
  for (int k=0;k<8;++k) pk.us[k]=f2bf(e[k]);
  return pk.u4;
}

// ---------- 4-bit linear codec: K in [e^-1, 1]; K = A4 + B4*n ----------
#define A4 0.36787944f
#define B4 0.042141372f
#define INVB4 23.729603f
__device__ __forceinline__ uint e4(float f){
  float q = (f - A4) * INVB4;
  int n = (int)(q + 0.5f);
  n = n < 0 ? 0 : (n > 15 ? 15 : n);
  return (uint)n;
}
__device__ __forceinline__ void d4x8(uint w, float* e){
#pragma unroll
  for (int k=0;k<8;++k)
    e[k] = A4 + B4 * (float)((w >> (4*k)) & 15u);
}

// ---------- wave/block reduce helpers (wave = 64) ----------
__device__ __forceinline__ float waveSum(float v){
#pragma unroll
  for (int o=32;o>0;o>>=1) v += __shfl_down(v,o);
  return v;
}
__device__ __forceinline__ float waveMax(float v){
#pragma unroll
  for (int o=32;o>0;o>>=1) v = fmaxf(v,__shfl_down(v,o));
  return v;
}
__device__ __forceinline__ float waveMin(float v){
#pragma unroll
  for (int o=32;o>0;o>>=1) v = fminf(v,__shfl_down(v,o));
  return v;
}
__device__ __forceinline__ float blkSum(float v, float* red){
  v = waveSum(v);
  if ((threadIdx.x&63)==0) red[threadIdx.x>>6] = v;
  __syncthreads();
  float r = red[0]+red[1]+red[2]+red[3];
  __syncthreads();
  return r;
}

// ---------- W transpose+convert (both weights): Wt[z][n][k] bf16 ----------
__global__ __launch_bounds__(256) void transposeW2(const float* __restrict__ W0,
                                                   const float* __restrict__ W1,
                                                   ushort* __restrict__ Wtb)
{
  __shared__ ushort T[128][72];
  const int z = blockIdx.y;
  const float* W = z ? W1 : W0;
  ushort* Wt = Wtb + (size_t)z*FF*EK;
  const int k0 = blockIdx.x*64, tid = threadIdx.x;
#pragma unroll
  for (int it=0; it<8; ++it){
    int f = tid + it*256;
    int r = f >> 5, c4 = f & 31;
    float4 v = *(const float4*)&W[(size_t)(k0+r)*FF + c4*4];
    T[c4*4+0][r]=f2bf(v.x); T[c4*4+1][r]=f2bf(v.y);
    T[c4*4+2][r]=f2bf(v.z); T[c4*4+3][r]=f2bf(v.w);
  }
  __syncthreads();
#pragma unroll
  for (int it=0; it<4; ++it){
    int f = tid + it*256;
    int n = f >> 3, c8 = f & 7;
    *(uint4*)&Wt[(size_t)n*EK + k0 + c8*8] = *(uint4*)&T[n][c8*8];
  }
}

// ---------- MFMA embed GEMM, both matrices, split-K=32, NT, bf16 partials ----------
__global__ __launch_bounds__(256) void embed_mfma2(const float* __restrict__ A0,
                                                   const float* __restrict__ A1,
                                                   const ushort* __restrict__ Wtb,
                                                   ushort* __restrict__ partb)
{
  __shared__ char smem[64*72*2 + 128*72*2];
  ushort (*Al)[72] = (ushort(*)[72])smem;
  ushort (*Wl)[72] = (ushort(*)[72])(smem + 64*72*2);
  float  (*Cst)[130] = (float(*)[130])smem;

  const int tid = threadIdx.x;
  const int z = blockIdx.z;
  const float* A = z ? A1 : A0;
  const ushort* Wt = Wtb + (size_t)z*FF*EK;
  ushort* part = partb + (size_t)z*KS*NN*FF;
  const int m0 = blockIdx.x * 64;
  const int kc = blockIdx.y * (EK/KS);
  const int w = tid >> 6, l = tid & 63;
  const int wr = w >> 1, wc = w & 1;
  const int lrow = l & 15, lk = (l >> 4) * 8;
  f32x4 acc[2][4];
#pragma unroll
  for (int mi=0;mi<2;++mi)
#pragma unroll
    for (int ni=0;ni<4;++ni) acc[mi][ni] = (f32x4){0.f,0.f,0.f,0.f};

  f32x4 aReg[4];
  uint4  wReg[4];
  auto gload = [&](int k0){
#pragma unroll
    for (int it=0;it<4;++it){
      int f = tid + it*256;
      int r = f >> 4, c4 = f & 15;
      aReg[it] = __builtin_nontemporal_load((const f32x4*)&A[(size_t)(m0+r)*EK + k0 + c4*4]);
    }
#pragma unroll
    for (int it=0;it<4;++it){
      int f = tid + it*256;
      int r = f >> 3, c8 = f & 7;
      wReg[it] = *(const uint4*)&Wt[(size_t)r*EK + k0 + c8*8];
    }
  };

  const int NSTEP = (EK/KS)/64;
  gload(kc);
  for (int step=0; step<NSTEP; ++step){
    __syncthreads();
#pragma unroll
    for (int it=0;it<4;++it){
      int f = tid + it*256;
      int r = f >> 4, c4 = f & 15;
      f32x4 a4 = aReg[it];
      union { ushort us[4]; uint2 u2; } pk;
      pk.us[0]=f2bf(a4[0]); pk.us[1]=f2bf(a4[1]); pk.us[2]=f2bf(a4[2]); pk.us[3]=f2bf(a4[3]);
      *(uint2*)&Al[r][c4*4] = pk.u2;
    }
#pragma unroll
    for (int it=0;it<4;++it){
      int f = tid + it*256;
      int r = f >> 3, c8 = f & 7;
      *(uint4*)&Wl[r][c8*8] = wReg[it];
    }
    __syncthreads();
    if (step+1 < NSTEP) gload(kc + (step+1)*64);
#pragma unroll
    for (int ksub = 0; ksub < 2; ++ksub) {
      bf16x8 af[2], bfr[4];
#pragma unroll
      for (int mi=0;mi<2;++mi) af[mi] = *(bf16x8*)&Al[wr*32+mi*16+lrow][ksub*32+lk];
#pragma unroll
      for (int ni=0;ni<4;++ni) bfr[ni] = *(bf16x8*)&Wl[wc*64+ni*16+lrow][ksub*32+lk];
#pragma unroll
      for (int mi=0;mi<2;++mi)
#pragma unroll
        for (int ni=0;ni<4;++ni)
          acc[mi][ni] = __builtin_amdgcn_mfma_f32_16x16x32_bf16(af[mi], bfr[ni], acc[mi][ni], 0,0,0);
    }
  }
  // ---- coalesced epilogue: stage fp32 in LDS, store bf16 NT (ull) ----
#pragma unroll
  for (int half=0; half<2; ++half){
    __syncthreads();
    if (wr == half){
#pragma unroll
      for (int mi=0;mi<2;++mi)
#pragma unroll
        for (int ni=0;ni<4;++ni)
#pragma unroll
          for (int r=0;r<4;++r){
            int rr = mi*16 + (l>>4)*4 + r;
            int col = wc*64 + ni*16 + lrow;
            Cst[rr][col] = acc[mi][ni][r];
          }
    }
    __syncthreads();
#pragma unroll
    for (int it=0;it<4;++it){
      int f = tid + it*256;
      int rr = f >> 5, g = f & 31;
      float4 o = *(float4*)&Cst[rr][g*4];
      union { ushort us[4]; ull u8; } pk;
      pk.us[0]=f2bf(o.x); pk.us[1]=f2bf(o.y); pk.us[2]=f2bf(o.z); pk.us[3]=f2bf(o.w);
      __builtin_nontemporal_store(pk.u8,
        (ull*)&part[((size_t)blockIdx.y*NN + m0 + half*32 + rr)*FF + g*4]);
    }
  }
}

// ---------- reduce bf16 split-K partials + bias + l2norm, both matrices ----------
__global__ __launch_bounds__(128) void reduce_l2_2(const ushort* __restrict__ partb,
                                                   const float* __restrict__ b0,
                                                   const float* __restrict__ b1,
                                                   float* __restrict__ o0,
                                                   float* __restrict__ o1,
                                                   ushort* __restrict__ ob0,
                                                   ushort* __restrict__ ob1)
{
  __shared__ float red[2];
  const int z = blockIdx.y;
  const ushort* part = partb + (size_t)z*KS*NN*FF;
  const float* bias = z ? b1 : b0;
  float* out = z ? o1 : o0;
  ushort* outb = z ? ob1 : ob0;
  int i = blockIdx.x, t = threadIdx.x;
  float s = bias[t];
#pragma unroll
  for (int ks=0; ks<KS; ++ks) s += bf2f(part[((size_t)ks*NN + i)*FF + t]);
  float q = waveSum(s*s);
  if ((t&63)==0) red[t>>6]=q;
  __syncthreads();
  float val = s / sqrtf(red[0]+red[1]);
  out[(size_t)i*FF+t] = val;
  outb[(size_t)i*FF+t] = f2bf(val);
}

// ---------- softmax rows (both): Sb bf16 [4096][128] padded, w = ||S_row|| ----------
__global__ __launch_bounds__(128) void softmax_rows2(const float* __restrict__ l0,
                                                     const float* __restrict__ l1,
                                                     ushort* __restrict__ Sb0,
                                                     ushort* __restrict__ Sb1,
                                                     float* __restrict__ w0,
                                                     float* __restrict__ w1)
{
  __shared__ float sm[2], ss[2], sq[2];
  const int z = blockIdx.y;
  const float* l = z ? l1 : l0;
  ushort* Sb = z ? Sb1 : Sb0;
  float* w = z ? w1 : w0;
  int i = blockIdx.x, t = threadIdx.x;
  int lane = t & 63, wid = t >> 6;
  float x = (t < CD) ? l[(size_t)i*CD + t] : -3.4e38f;
  float m = waveMax(x);
  if (lane==0) sm[wid]=m;
  __syncthreads();
  m = fmaxf(sm[0], sm[1]);
  float e = (t < CD) ? __expf(x - m) : 0.f;
  float s = waveSum(e);
  if (lane==0) ss[wid]=s;
  __syncthreads();
  float tot = ss[0]+ss[1];
  float sv = e / tot;
  Sb[(size_t)i*FF + t] = (t < CD) ? f2bf(sv) : (ushort)0;
  float q = waveSum(sv*sv);
  if (lane==0) sq[wid]=q;
  __syncthreads();
  if (t==0) w[i] = sqrtf(sq[0]+sq[1]);
}

// ---------- top-7 select from raw bf16 dot matrix, both matrices ----------
__global__ __launch_bounds__(256) void knn_select2(const ushort* __restrict__ Ds,
                                                   const ushort* __restrict__ Dt,
                                                   const float* __restrict__ w_s,
                                                   const float* __restrict__ w_t,
                                                   int* __restrict__ idx_s,
                                                   int* __restrict__ idx_t)
{
  __shared__ float redv[256];
  __shared__ int   redi[256];
  const int z = blockIdx.y;
  const ushort* D = z ? Dt : Ds;
  const float* w = z ? w_t : w_s;
  int* idx = z ? idx_t : idx_s;
  int i = blockIdx.x, tid = threadIdx.x;
  float wi = w[i];
  float bv[7]; int bi[7];
#pragma unroll
  for (int m=0;m<7;++m){ bv[m]=-3.4e38f; bi[m]=-1; }
  const uint4* row4 = (const uint4*)&D[(size_t)i*NN];
#pragma unroll
  for (int ss=0;ss<2;++ss){
    int j8 = tid + ss*256;
    float e[8]; unpack8(row4[j8], e);
#pragma unroll
    for (int q=0;q<8;++q){
      int j = j8*8 + q;
      float cv = e[q] / fmaxf(wi * w[j], 1e-7f);
      cv = (j==i) ? -3.4e38f : cv;
      if (cv > bv[6]) {
        int m = 6;
        while (m > 0 && cv > bv[m-1]) { bv[m]=bv[m-1]; bi[m]=bi[m-1]; --m; }
        bv[m]=cv; bi[m]=j;
      }
    }
  }
  if (tid==0) idx[(size_t)i*8] = i;
  for (int m=0;m<7;++m) {
    redv[tid]=bv[0]; redi[tid]=tid;
    __syncthreads();
    for (int s=128;s>=1;s>>=1) {
      if (tid < s) {
        if (redv[tid+s] > redv[tid]) { redv[tid]=redv[tid+s]; redi[tid]=redi[tid+s]; }
      }
      __syncthreads();
    }
    int wt = redi[0];
    if (tid == wt) {
      idx[(size_t)i*8 + 1 + m] = bi[0];
#pragma unroll
      for (int q=0;q<6;++q){ bv[q]=bv[q+1]; bi[q]=bi[q+1]; }
      bv[6]=-3.4e38f; bi[6]=-1;
    }
    __syncthreads();
  }
}

// ---------- encoder (both): outb = bf16(l2norm(concat(h, mean(h[idx])) @ W + b)) ----------
__global__ __launch_bounds__(128) void encoder_kernel2(const float* __restrict__ h0,
                                                       const float* __restrict__ h1,
                                                       const int* __restrict__ idx0,
                                                       const int* __restrict__ idx1,
                                                       const float* __restrict__ W0,
                                                       const float* __restrict__ W1,
                                                       const float* __restrict__ bb0,
                                                       const float* __restrict__ bb1,
                                                       ushort* __restrict__ o0,
                                                       ushort* __restrict__ o1)
{
  __shared__ float hin[256];
  __shared__ float sred[2];
  const int z = blockIdx.y;
  const float* h = z ? h1 : h0;
  const int* idx = z ? idx1 : idx0;
  const float* W = z ? W1 : W0;
  const float* bias = z ? bb1 : bb0;
  ushort* outb = z ? o1 : o0;
  int i = blockIdx.x, t = threadIdx.x;
  float hv = h[(size_t)i*FF + t];
  float agg = 0.f;
#pragma unroll
  for (int m=0;m<8;++m) agg += h[(size_t)idx[i*8+m]*FF + t];
  agg *= 0.125f;
  hin[t] = hv; hin[FF + t] = agg;
  __syncthreads();
  float acc = bias[t];
  for (int k=0;k<256;++k) acc += hin[k] * W[(size_t)k*FF + t];
  float s = waveSum(acc*acc);
  int lane = t & 63, wid = t >> 6;
  if (lane==0) sred[wid]=s;
  __syncthreads();
  float tot = sred[0]+sred[1];
  outb[(size_t)i*FF + t] = f2bf(acc / sqrtf(tot));
}

// ---------- MFMA: C bf16 = A bf16 @ B^T, z-select inputs, optional stats ----------
__global__ __launch_bounds__(256) void gemm_btb_mfma(const ushort* __restrict__ A0,
                                                     const ushort* __restrict__ B0,
                                                     ushort* __restrict__ C0,
                                                     const ushort* __restrict__ A1,
                                                     const ushort* __restrict__ B1,
                                                     ushort* __restrict__ C1,
                                                     float* __restrict__ rmaxp,
                                                     float* __restrict__ gminp)
{
  __shared__ ushort Al[64][136];
  __shared__ ushort Bl[64][136];
  __shared__ float rmx2[64][2];
  __shared__ float gmnw[4];
  const int z = blockIdx.z;
  const ushort* A = z ? A1 : A0;
  const ushort* B = z ? B1 : B0;
  ushort* C = z ? C1 : C0;
  float* rmaxpz = rmaxp ? (rmaxp + (size_t)z*64*NN) : nullptr;
  float* gminpz = gminp ? (gminp + (size_t)z*4096) : nullptr;
  const int tid = threadIdx.x;
  const int i0 = blockIdx.y*64, j0 = blockIdx.x*64;
#pragma unroll
  for (int it=0; it<4; ++it){
    int f = tid + it*256;
    int r = f >> 4, c8 = f & 15;
    *(uint4*)&Al[r][c8*8] = *(const uint4*)&A[(size_t)(i0+r)*FF + c8*8];
    *(uint4*)&Bl[r][c8*8] = *(const uint4*)&B[(size_t)(j0+r)*FF + c8*8];
  }
  __syncthreads();
  const int w = tid>>6, l = tid&63;
  const int wr = w>>1, wc = w&1;
  const int lrow = l&15, lk = (l>>4)*8;
  f32x4 acc[2][2];
#pragma unroll
  for (int mi=0;mi<2;++mi)
#pragma unroll
    for (int ni=0;ni<2;++ni) acc[mi][ni] = (f32x4){0.f,0.f,0.f,0.f};
#pragma unroll
  for (int ks=0; ks<4; ++ks){
    bf16x8 af[2], bfm[2];
#pragma unroll
    for (int mi=0;mi<2;++mi) af[mi] = *(bf16x8*)&Al[wr*32+mi*16+lrow][ks*32+lk];
#pragma unroll
    for (int ni=0;ni<2;++ni) bfm[ni] = *(bf16x8*)&Bl[wc*32+ni*16+lrow][ks*32+lk];
#pragma unroll
    for (int mi=0;mi<2;++mi)
#pragma unroll
      for (int ni=0;ni<2;++ni)
        acc[mi][ni] = __builtin_amdgcn_mfma_f32_16x16x32_bf16(af[mi], bfm[ni], acc[mi][ni], 0,0,0);
  }
  if (rmaxpz){
    float rowm[8]; float gmn = 3.4e38f;
#pragma unroll
    for (int mi=0;mi<2;++mi)
#pragma unroll
      for (int r=0;r<4;++r){
        float a = fmaxf(acc[mi][0][r], acc[mi][1][r]);
        float c = fminf(acc[mi][0][r], acc[mi][1][r]);
        rowm[mi*4+r] = a;
        gmn = fminf(gmn, c);
      }
#pragma unroll
    for (int mo=1; mo<16; mo<<=1){
#pragma unroll
      for (int q=0;q<8;++q) rowm[q] = fmaxf(rowm[q], __shfl_xor(rowm[q], mo));
      gmn = fminf(gmn, __shfl_xor(gmn, mo));
    }
    if (lrow == 0){
#pragma unroll
      for (int mi=0;mi<2;++mi)
#pragma unroll
        for (int r=0;r<4;++r)
          rmx2[wr*32 + mi*16 + (l>>4)*4 + r][wc] = rowm[mi*4+r];
    }
    gmn = fminf(gmn, __shfl_xor(gmn, 16));
    gmn = fminf(gmn, __shfl_xor(gmn, 32));
    if (l==0) gmnw[w] = gmn;
    __syncthreads();
    if (tid < 64)
      rmaxpz[(size_t)blockIdx.x*NN + i0 + tid] = fmaxf(rmx2[tid][0], rmx2[tid][1]);
    if (tid == 0)
      gminpz[blockIdx.y*64 + blockIdx.x] = fminf(fminf(gmnw[0],gmnw[1]),fminf(gmnw[2],gmnw[3]));
  }
  __syncthreads();
  ushort (*Cl)[72] = (ushort(*)[72])&Al[0][0];
#pragma unroll
  for (int mi=0;mi<2;++mi)
#pragma unroll
    for (int ni=0;ni<2;++ni)
#pragma unroll
      for (int r=0;r<4;++r){
        int row = wr*32 + mi*16 + (l>>4)*4 + r;
        int col = wc*32 + ni*16 + lrow;
        Cl[row][col] = f2bf(acc[mi][ni][r]);
      }
  __syncthreads();
#pragma unroll
  for (int it=0; it<2; ++it){
    int f = tid + it*256;
    int r = f >> 3, c8 = f & 7;
    *(uint4*)&C[(size_t)(i0+r)*NN + j0 + c8*8] = *(uint4*)&Cl[r][c8*8];
  }
}

// ---------- rowmax finalize (z=2): 4 threads per row ----------
__global__ __launch_bounds__(256) void rowstat2b(const float* __restrict__ rmaxp2,
                                                 float* __restrict__ rmax2)
{
  const int z = blockIdx.y;
  const float* rmaxp = rmaxp2 + (size_t)z*64*NN;
  float* rmax = rmax2 + (size_t)z*NN;
  int t = threadIdx.x;
  int row = blockIdx.x*64 + (t >> 2);
  int q = t & 3;
  float m = -3.4e38f;
#pragma unroll
  for (int b=0;b<16;++b) m = fmaxf(m, rmaxp[(size_t)(q*16+b)*NN + row]);
  m = fmaxf(m, __shfl_xor(m, 1));
  m = fmaxf(m, __shfl_xor(m, 2));
  if (q==0) rmax[row] = m;
}

// ---------- stat finalize (z=2): stat = {gmin, 1/(gmax-gmin)} ----------
__global__ __launch_bounds__(256) void greduce2b(const float* __restrict__ rmax2,
                                                 const float* __restrict__ gminp2,
                                                 float* __restrict__ stat2)
{
  __shared__ float r1[4], r2[4];
  const int z = blockIdx.x;
  const float* rmax = rmax2 + (size_t)z*NN;
  const float* gminp = gminp2 + (size_t)z*4096;
  int t = threadIdx.x;
  float mx=-3.4e38f, mn=3.4e38f;
  for (int i=t; i<NN; i+=256){
    mx = fmaxf(mx, rmax[i]);
    mn = fminf(mn, gminp[i]);
  }
  mx = waveMax(mx); mn = waveMin(mn);
  int lane = t & 63, wid = t >> 6;
  if (lane==0){ r1[wid]=mx; r2[wid]=mn; }
  __syncthreads();
  if (t==0){
    float gmx = fmaxf(fmaxf(r1[0],r1[1]),fmaxf(r1[2],r1[3]));
    float gmn = fminf(fminf(r2[0],r2[1]),fminf(r2[2],r2[3]));
    stat2[z*2]   = gmn;
    stat2[z*2+1] = 1.f/(gmx-gmn);
  }
}

// ---------- transform (z=2): K4 = 4bit(exp((M0 - rowmax)*scale)); M out for idx==3 ----------
__global__ __launch_bounds__(256) void transform_b2(const ushort* __restrict__ stage2,
                                                    uint* __restrict__ K4,
                                                    const float* __restrict__ rmax2,
                                                    const float* __restrict__ stat2,
                                                    float* __restrict__ Mout, int g)
{
  const int z = blockIdx.y;
  const int idx = g*2 + z;
  const ushort* stage = stage2 + (size_t)z*NN*NN;
  uint* K4m = K4 + (size_t)idx*NN*(NN/8);
  const float* rmax = rmax2 + (size_t)z*NN;
  const float gmin = stat2[z*2], scale = stat2[z*2+1];
  const bool wM = (idx == 3) && (Mout != nullptr);
  const uint4* Km = (const uint4*)stage;
  const int total8 = (NN*NN)/8;
  for (int f = blockIdx.x*256 + threadIdx.x; f < total8; f += gridDim.x*256){
    int i = f >> 9;
    float rm = rmax[i];
    float e[8]; unpack8(Km[f], e);
    uint o = 0;
#pragma unroll
    for (int k=0;k<8;++k) o |= e4(__expf((e[k]-rm)*scale)) << (4*k);
    K4m[f] = o;
    if (wM){
      float4 o1, o2;
      o1.x=(e[0]-gmin)*scale; o1.y=(e[1]-gmin)*scale; o1.z=(e[2]-gmin)*scale; o1.w=(e[3]-gmin)*scale;
      o2.x=(e[4]-gmin)*scale; o2.y=(e[5]-gmin)*scale; o2.z=(e[6]-gmin)*scale; o2.w=(e[7]-gmin)*scale;
      float4* mp = (float4*)(Mout + (size_t)f*8);
      mp[0]=o1; mp[1]=o2;
    }
  }
}

// ---------- init: v=1 for all 4 matrices ----------
__global__ void vinit4(float* __restrict__ v)
{
  int g = blockIdx.x*256 + threadIdx.x;
  if (g < 4*NN) v[g] = 1.f;
}

// ---------- fused sinkhorn iteration over 4-bit K, paired-row barriers ----------
__global__ __launch_bounds__(256) void sink_fused(const uint* __restrict__ K4base,
                                                  const float* __restrict__ vv,
                                                  ushort* __restrict__ part)
{
  __shared__ float red2[2][4];
  const int m = blockIdx.y, b = blockIdx.x, t = threadIdx.x;
  const int i0 = b*CHUNK;
  const uint* K4 = K4base + (size_t)m*NN*(NN/8);
  const float4* v4 = (const float4*)(vv + (size_t)m*NN);
  const int lane = t & 63, wid = t >> 6;
  float vs[16];
  {
    float4 A=v4[t*4+0], B=v4[t*4+1], C=v4[t*4+2], D=v4[t*4+3];
    vs[0]=A.x; vs[1]=A.y; vs[2]=A.z; vs[3]=A.w;
    vs[4]=B.x; vs[5]=B.y; vs[6]=B.z; vs[7]=B.w;
    vs[8]=C.x; vs[9]=C.y; vs[10]=C.z; vs[11]=C.w;
    vs[12]=D.x; vs[13]=D.y; vs[14]=D.z; vs[15]=D.w;
  }
  float vsum = 0.f;
#pragma unroll
  for (int k=0;k<16;++k) vsum += vs[k];
  float colacc[16];
#pragma unroll
  for (int k=0;k<16;++k) colacc[k]=0.f;
  for (int r=0;r<CHUNK;r+=2){
    uint2 kw0 = ((const uint2*)(K4 + (size_t)(i0+r  )*(NN/8)))[t];
    uint2 kw1 = ((const uint2*)(K4 + (size_t)(i0+r+1)*(NN/8)))[t];
    float s0 = 0.f, s1 = 0.f;
#pragma unroll
    for (int k=0;k<8;++k){
      s0 += (float)((kw0.x >> (4*k)) & 15u) * vs[k];
      s0 += (float)((kw0.y >> (4*k)) & 15u) * vs[k+8];
      s1 += (float)((kw1.x >> (4*k)) & 15u) * vs[k];
      s1 += (float)((kw1.y >> (4*k)) & 15u) * vs[k+8];
    }
    float d0 = waveSum(A4*vsum + B4*s0);
    float d1 = waveSum(A4*vsum + B4*s1);
    if (lane==0){ red2[0][wid]=d0; red2[1][wid]=d1; }
    __syncthreads();
    float ur0 = RVAL / (red2[0][0]+red2[0][1]+red2[0][2]+red2[0][3]);
    float ur1 = RVAL / (red2[1][0]+red2[1][1]+red2[1][2]+red2[1][3]);
    __syncthreads();
    const float a0 = A4*ur0 + A4*ur1;
    const float b0 = B4*ur0, b1 = B4*ur1;
#pragma unroll
    for (int k=0;k<8;++k){
      colacc[k]   += a0 + b0*(float)((kw0.x >> (4*k)) & 15u) + b1*(float)((kw1.x >> (4*k)) & 15u);
      colacc[k+8] += a0 + b0*(float)((kw0.y >> (4*k)) & 15u) + b1*(float)((kw1.y >> (4*k)) & 15u);
    }
  }
  ushort* prow = part + ((size_t)m*NCH + b)*NN;
  ((uint4*)prow)[t*2]   = pack8(colacc);
  ((uint4*)prow)[t*2+1] = pack8(colacc+8);
}

// ---------- column finish: v[j] = R / sum_b part[m][b][j]; 64 cols/block ----------
__global__ __launch_bounds__(256) void colfin_b(const ushort* __restrict__ part,
                                                float* __restrict__ vv)
{
  __shared__ float lds[32][8][9];
  const int m = blockIdx.y, bx = blockIdx.x, t = threadIdx.x;
  const int g = t & 7;
  const int tq = t >> 3;
  const uint4* pb = (const uint4*)(part + (size_t)m*NCH*NN);
  float acc[8];
#pragma unroll
  for (int k=0;k<8;++k) acc[k]=0.f;
#pragma unroll
  for (int s=0;s<8;++s){
    int b = tq + s*32;
    float e[8]; unpack8(pb[(size_t)b*512 + bx*8 + g], e);
#pragma unroll
    for (int k=0;k<8;++k) acc[k] += e[k];
  }
#pragma unroll
  for (int k=0;k<8;++k) lds[tq][g][k] = acc[k];
  __syncthreads();
  if (t < 64){
    int gg = t >> 3, c = t & 7;
    float s = 0.f;
#pragma unroll
    for (int q=0;q<32;++q) s += lds[q][gg][c];
    vv[(size_t)m*NN + bx*64 + gg*8 + c] = RVAL / s;
  }
}

// ---------- final: y = Kv ; P = K v_j / y ; per-row loss partial ----------
__global__ __launch_bounds__(256) void loss2_b(const uint* __restrict__ K4base,
                                               const float* __restrict__ vv,
                                               float* __restrict__ accf,
                                               float* __restrict__ Pout, int finalm)
{
  __shared__ float red[4];
  int m = blockIdx.y, i = blockIdx.x, t = threadIdx.x;
  const uint2* row = (const uint2*)(K4base + ((size_t)m*NN + i)*(NN/8));
  const float4* v4 = (const float4*)(vv + (size_t)m*NN);
  uint2 kw = row[t];
  float e[16];
  d4x8(kw.x, e); d4x8(kw.y, e+8);
  float vr[16];
  {
    float4 A=v4[t*4+0], B=v4[t*4+1], C=v4[t*4+2], D=v4[t*4+3];
    vr[0]=A.x; vr[1]=A.y; vr[2]=A.z; vr[3]=A.w;
    vr[4]=B.x; vr[5]=B.y; vr[6]=B.z; vr[7]=B.w;
    vr[8]=C.x; vr[9]=C.y; vr[10]=C.z; vr[11]=C.w;
    vr[12]=D.x; vr[13]=D.y; vr[14]=D.z; vr[15]=D.w;
  }
  float s = 0.f;
#pragma unroll
  for (int k=0;k<16;++k) s += e[k]*vr[k];
  float y = blkSum(s, red);
  float invy = 1.f / y;
  const bool wp = (m==finalm) && (Pout != nullptr);
  const int j0 = t*16;
  float p[16];
#pragma unroll
  for (int k=0;k<16;++k) p[k] = e[k]*vr[k]*invy;
  if (wp){
    float4* pp = (float4*)(Pout + (size_t)i*NN + j0);
#pragma unroll
    for (int q=0;q<4;++q){
      float4 o; o.x=p[q*4]; o.y=p[q*4+1]; o.z=p[q*4+2]; o.w=p[q*4+3];
      pp[q]=o;
    }
  }
  float local = 0.f;
#pragma unroll
  for (int k=0;k<16;++k){
    float d = p[k] - ((j0+k)==i ? 1.f : 0.f);
    local += d*d;
  }
  float tot = blkSum(local, red);
  if (t==0) accf[(size_t)m*NN + i] = tot;
}

// ---------- all four losses + total in one kernel ----------
__global__ __launch_bounds__(256) void lossfin_all(const float* __restrict__ accf,
                                                   float* __restrict__ out)
{
  __shared__ float red[4];
  int t = threadIdx.x;
  float L[4];
#pragma unroll
  for (int m=0;m<4;++m){
    float s = 0.f;
#pragma unroll
    for (int q=0;q<16;++q) s += accf[(size_t)m*NN + t + q*256];
    float tot = blkSum(s, red);
    L[m] = sqrtf(tot);
  }
  if (t==0){
    out[1]=L[0]; out[3]=L[1]; out[4]=L[2]; out[2]=L[3];
    out[0]=L[0]+L[1]+L[2]+L[3];
  }
}

extern "C" void kernel_launch(void* const* d_in, const int* in_sizes, int n_in,
                              void* d_out, int out_size, void* d_ws, size_t ws_size,
                              hipStream_t stream)
{
  (void)in_sizes; (void)n_in; (void)out_size; (void)ws_size;
  const float* f_s  = (const float*)d_in[1];
  const float* l_s  = (const float*)d_in[2];
  const float* f_t  = (const float*)d_in[3];
  const float* l_t  = (const float*)d_in[4];
  const float* W_es = (const float*)d_in[5];
  const float* b_es = (const float*)d_in[6];
  const float* W_et = (const float*)d_in[7];
  const float* b_et = (const float*)d_in[8];
  const float* W_gs = (const float*)d_in[9];
  const float* b_gs = (const float*)d_in[10];
  const float* W_gt = (const float*)d_in[11];
  const float* b_gt = (const float*)d_in[12];
  float* out = (float*)d_out;

  char* ws = (char*)d_ws;
  size_t off = 0;
  auto alloc = [&](size_t nbytes)->void*{
    off = (off + 255) & ~(size_t)255;
    void* p = ws + off; off += nbytes; return p;
  };
  float* f_es = (float*)alloc((size_t)NN*FF*4);
  float* f_et = (float*)alloc((size_t)NN*FF*4);
  // fb base: 4 consecutive 1MB bf16 feature buffers (order: es, et, gs, gt)
  ushort* f_esb = (ushort*)alloc((size_t)NN*FF*2);
  ushort* f_etb = (ushort*)alloc((size_t)NN*FF*2);
  ushort* f_gsb = (ushort*)alloc((size_t)NN*FF*2);
  ushort* f_gtb = (ushort*)alloc((size_t)NN*FF*2);
  ushort* Sb_s = (ushort*)alloc((size_t)NN*FF*2);
  ushort* Sb_t = (ushort*)alloc((size_t)NN*FF*2);
  float* w_s  = (float*)alloc(NN*4);
  float* w_t  = (float*)alloc(NN*4);
  int*   idx_s= (int*)alloc(NN*8*4);
  int*   idx_t= (int*)alloc(NN*8*4);
  float* rmax2 = (float*)alloc((size_t)2*NN*4);
  float* rmaxp2= (float*)alloc((size_t)2*64*NN*4);   // 2 MB
  float* gminp2= (float*)alloc((size_t)2*4096*4);
  float* stat2 = (float*)alloc(64);
  float* v    = (float*)alloc((size_t)4*NN*4);
  float* accf = (float*)alloc((size_t)4*NN*4);
  ushort* part = (ushort*)alloc((size_t)4*NCH*NN*2);   // 8 MB
  ushort* Wt0  = (ushort*)alloc((size_t)2*FF*EK*2);    // 4 MB
  off = (off + 255) & ~(size_t)255;
  ushort* stage2 = (ushort*)(ws + off);        // 64 MB: two bf16 M0 buffers
  uint* K4 = (uint*)(stage2 + (size_t)2*NN*NN);// 32 MB 4-bit, 4 matrices
  // pre-OT overlays:
  ushort* epart = stage2;                      // 64 MB bf16 embed partials
  ushort* Db_s  = stage2;                      // 32 MB bf16 raw dot (knn s)
  ushort* Db_t  = stage2 + (size_t)NN*NN;      // 32 MB bf16 raw dot (knn t)

  float* Pout_final = out + 5;
  float* Mout_final = out + 5 + (size_t)NN*NN;

  // ---- embeddings (MFMA split-K=32, both matrices, NT, bf16 partials) ----
  transposeW2<<<dim3(EK/64,2),256,0,stream>>>(W_es, W_et, Wt0);
  embed_mfma2<<<dim3(64,KS,2),256,0,stream>>>(f_s, f_t, Wt0, epart);
  reduce_l2_2<<<dim3(NN,2),128,0,stream>>>(epart, b_es, b_et, f_es, f_et, f_esb, f_etb);

  // ---- knn path: MFMA raw-dot matrices (both in one launch) + weighted select ----
  softmax_rows2<<<dim3(NN,2),128,0,stream>>>(l_s, l_t, Sb_s, Sb_t, w_s, w_t);
  gemm_btb_mfma<<<dim3(64,64,2),256,0,stream>>>(Sb_s, Sb_s, Db_s, Sb_t, Sb_t, Db_t,
                                                nullptr, nullptr);
  knn_select2<<<dim3(NN,2),256,0,stream>>>(Db_s, Db_t, w_s, w_t, idx_s, idx_t);
  encoder_kernel2<<<dim3(NN,2),128,0,stream>>>(f_es, f_et, idx_s, idx_t,
                                               W_gs, W_gt, b_gs, b_gt, f_gsb, f_gtb);

  // ---- OT: pairwise-batched build (z=2), then 4-batched sinkhorn ----
  // matrices: m0=(et,es) m1=(gt,es) m2=(et,gt) m3=(gt,gs)
  const ushort* ftab[4] = { f_etb, f_gtb, f_etb, f_gtb };
  const ushort* fsab[4] = { f_esb, f_esb, f_gtb, f_gsb };

  vinit4<<<(4*NN+255)/256,256,0,stream>>>(v);
  for (int g=0; g<2; ++g){
    gemm_btb_mfma<<<dim3(64,64,2),256,0,stream>>>(
        ftab[g*2+0], fsab[g*2+0], stage2,
        ftab[g*2+1], fsab[g*2+1], stage2 + (size_t)NN*NN,
        rmaxp2, gminp2);
    rowstat2b<<<dim3(NN/64,2),256,0,stream>>>(rmaxp2, rmax2);
    greduce2b<<<2,256,0,stream>>>(rmax2, gminp2, stat2);
    transform_b2<<<dim3(2048,2),256,0,stream>>>(stage2, K4, rmax2, stat2,
                                                Mout_final, g);
  }
  for (int it=0; it<OT_ITERS; ++it){
    sink_fused<<<dim3(NCH,4),256,0,stream>>>(K4, v, part);
    colfin_b<<<dim3(64,4),256,0,stream>>>(part, v);
  }
  loss2_b<<<dim3(NN,4),256,0,stream>>>(K4, v, accf, Pout_final, 3);
  lossfin_all<<<1,256,0,stream>>>(accf, out);
}